// Round 1
// baseline (29290.558 us; speedup 1.0000x reference)
//
#include <hip/hip_runtime.h>
#include <math.h>

// ---------------------------------------------------------------------------
// Direct Conv3d (k=3, pad=1, arbitrary stride). One thread per output voxel.
// Weights for the block's output channel o are staged in LDS (Ci*27 floats).
// grid: (ceil(Do*Ho*Wo/256), Co, N)
// ---------------------------------------------------------------------------
__global__ __launch_bounds__(256) void conv3d_k(
    const float* __restrict__ in, const float* __restrict__ wgt,
    const float* __restrict__ bias, float* __restrict__ out,
    int Ci, int Di, int Hi, int Wi, int Do, int Ho, int Wo,
    int sd, int sh, int sw)
{
    extern __shared__ float lw[];
    const int o = blockIdx.y, n = blockIdx.z;
    const int Co = gridDim.y;
    const int W27 = Ci * 27;
    for (int i = threadIdx.x; i < W27; i += blockDim.x)
        lw[i] = wgt[(size_t)o * W27 + i];
    __syncthreads();

    const int DoHoWo = Do * Ho * Wo;
    int sp = blockIdx.x * blockDim.x + threadIdx.x;
    if (sp >= DoHoWo) return;
    const int HoWo = Ho * Wo;
    int z = sp / HoWo, r = sp % HoWo, y = r / Wo, x = r % Wo;

    const int HWi = Hi * Wi;
    const float* inb = in + (size_t)n * Ci * Di * HWi;
    float acc = bias[o];
    for (int ci = 0; ci < Ci; ++ci) {
        const float* ip = inb + (size_t)ci * Di * HWi;
        const float* wp = lw + ci * 27;
        #pragma unroll
        for (int kd = 0; kd < 3; ++kd) {
            int zi = z * sd + kd - 1;
            if ((unsigned)zi >= (unsigned)Di) continue;
            const float* ipz = ip + (size_t)zi * HWi;
            #pragma unroll
            for (int kh = 0; kh < 3; ++kh) {
                int yi = y * sh + kh - 1;
                if ((unsigned)yi >= (unsigned)Hi) continue;
                const float* row = ipz + (size_t)yi * Wi;
                const float* wr = wp + (kd * 3 + kh) * 3;
                int xb = x * sw - 1;
                if (xb >= 0 && xb + 2 < Wi) {
                    acc += wr[0] * row[xb];
                    acc += wr[1] * row[xb + 1];
                    acc += wr[2] * row[xb + 2];
                } else {
                    #pragma unroll
                    for (int kw = 0; kw < 3; ++kw) {
                        int xi = xb + kw;
                        if ((unsigned)xi < (unsigned)Wi) acc += wr[kw] * row[xi];
                    }
                }
            }
        }
    }
    out[(size_t)(n * Co + o) * DoHoWo + sp] = acc;
}

// ---------------------------------------------------------------------------
// ConvTranspose3d (k=3, pad=1, output_padding via output dims) as gather:
// out[p] += w[o,ci,2-q] * in[(p+q-1)/s]  when (p+q-1) valid multiple of s.
// grid: (ceil(Do*Ho*Wo/256), Co, N)
// ---------------------------------------------------------------------------
__global__ __launch_bounds__(256) void convt3d_k(
    const float* __restrict__ in, const float* __restrict__ wgt,
    const float* __restrict__ bias, float* __restrict__ out,
    int Ci, int Di, int Hi, int Wi, int Do, int Ho, int Wo,
    int sd, int sh, int sw)
{
    extern __shared__ float lw[];
    const int o = blockIdx.y, n = blockIdx.z;
    const int Co = gridDim.y;
    const int W27 = Ci * 27;
    for (int i = threadIdx.x; i < W27; i += blockDim.x)
        lw[i] = wgt[(size_t)o * W27 + i];
    __syncthreads();

    const int DoHoWo = Do * Ho * Wo;
    int sp = blockIdx.x * blockDim.x + threadIdx.x;
    if (sp >= DoHoWo) return;
    const int HoWo = Ho * Wo;
    int z = sp / HoWo, r = sp % HoWo, y = r / Wo, x = r % Wo;

    const int HWi = Hi * Wi, DHWi = Di * HWi;
    const float* inb = in + (size_t)n * Ci * DHWi;
    const int Ldd = (Di - 1) * sd + 1, Ldh = (Hi - 1) * sh + 1, Ldw = (Wi - 1) * sw + 1;
    float acc = bias[o];
    #pragma unroll
    for (int qd = 0; qd < 3; ++qd) {
        int t = z + qd - 1;
        if (t < 0 || t >= Ldd || (t % sd)) continue;
        int id = t / sd;
        #pragma unroll
        for (int qh = 0; qh < 3; ++qh) {
            int u = y + qh - 1;
            if (u < 0 || u >= Ldh || (u % sh)) continue;
            int ih = u / sh;
            #pragma unroll
            for (int qw = 0; qw < 3; ++qw) {
                int v = x + qw - 1;
                if (v < 0 || v >= Ldw || (v % sw)) continue;
                int iw = v / sw;
                int ib = (id * Hi + ih) * Wi + iw;
                int widx = (2 - qd) * 9 + (2 - qh) * 3 + (2 - qw);
                const float* ip = inb + ib;
                const float* wp = lw + widx;
                float a2 = 0.f;
                #pragma unroll 4
                for (int ci = 0; ci < Ci; ++ci)
                    a2 += wp[ci * 27] * ip[(size_t)ci * DHWi];
                acc += a2;
            }
        }
    }
    out[(size_t)(n * Co + o) * DoHoWo + sp] = acc;
}

// ---------------------------------------------------------------------------
// BatchNorm batch statistics: one block per channel.
// ---------------------------------------------------------------------------
__global__ __launch_bounds__(256) void bn_stats_k(
    const float* __restrict__ in, float* __restrict__ mean, float* __restrict__ var,
    int C, int DHW, int N)
{
    int c = blockIdx.x;
    float s = 0.f, s2 = 0.f;
    for (int n = 0; n < N; ++n) {
        const float* p = in + (size_t)(n * C + c) * DHW;
        for (int i = threadIdx.x; i < DHW; i += blockDim.x) {
            float v = p[i];
            s += v; s2 += v * v;
        }
    }
    #pragma unroll
    for (int off = 32; off; off >>= 1) {
        s  += __shfl_down(s, off, 64);
        s2 += __shfl_down(s2, off, 64);
    }
    __shared__ float sh[4], sh2[4];
    int wid = threadIdx.x >> 6, lane = threadIdx.x & 63;
    if (lane == 0) { sh[wid] = s; sh2[wid] = s2; }
    __syncthreads();
    if (threadIdx.x == 0) {
        float S = sh[0] + sh[1] + sh[2] + sh[3];
        float S2 = sh2[0] + sh2[1] + sh2[2] + sh2[3];
        float cnt = (float)DHW * (float)N;
        float m = S / cnt;
        mean[c] = m;
        var[c] = S2 / cnt - m * m;
    }
}

// ---------------------------------------------------------------------------
// BN apply + LeakyReLU(0.2), in place, float4 vectorized. grid-stride.
// ---------------------------------------------------------------------------
__global__ __launch_bounds__(256) void bn_lrelu_k(
    float* __restrict__ buf, const float* __restrict__ mean, const float* __restrict__ var,
    const float* __restrict__ g, const float* __restrict__ b,
    int C, int DHW, unsigned int total4)
{
    unsigned int i = blockIdx.x * blockDim.x + threadIdx.x;
    unsigned int stride = gridDim.x * blockDim.x;
    for (; i < total4; i += stride) {
        unsigned int e = i * 4u;
        int c = (int)((e / (unsigned)DHW) % (unsigned)C);
        float m = mean[c], vv = var[c];
        float sc = g[c] * rsqrtf(vv + 1e-5f);
        float sb = b[c] - m * sc;
        float4 v = reinterpret_cast<float4*>(buf)[i];
        v.x = v.x * sc + sb; v.x = v.x >= 0.f ? v.x : 0.2f * v.x;
        v.y = v.y * sc + sb; v.y = v.y >= 0.f ? v.y : 0.2f * v.y;
        v.z = v.z * sc + sb; v.z = v.z >= 0.f ? v.z : 0.2f * v.z;
        v.w = v.w * sc + sb; v.w = v.w >= 0.f ? v.w : 0.2f * v.w;
        reinterpret_cast<float4*>(buf)[i] = v;
    }
}

// ---------------------------------------------------------------------------
// Row L2 norms of mem [K,256]. One 64-thread block per row.
// ---------------------------------------------------------------------------
__global__ __launch_bounds__(64) void rownorm_k(
    const float* __restrict__ mem, float* __restrict__ nrm, int C)
{
    int k = blockIdx.x;
    const float* p = mem + (size_t)k * C;
    float s = 0.f;
    for (int i = threadIdx.x; i < C; i += 64) { float v = p[i]; s += v * v; }
    #pragma unroll
    for (int off = 32; off; off >>= 1) s += __shfl_down(s, off, 64);
    if (threadIdx.x == 0) nrm[k] = sqrtf(s);
}

// ---------------------------------------------------------------------------
// Cosine-similarity scores: one block per z-row m (M=1024). C=256 hardcoded
// (N=2, D=2, H=16, W=16). scores[m*K+k] = dot/max(|z||m|,1e-8)
// ---------------------------------------------------------------------------
__global__ __launch_bounds__(256) void scores_k(
    const float* __restrict__ f, const float* __restrict__ mem,
    const float* __restrict__ mnorm, float* __restrict__ scores, int K)
{
    __shared__ __align__(16) float zrow[256];
    __shared__ float red[4];
    int m = blockIdx.x;
    int w = m & 15, h = (m >> 4) & 15, d = (m >> 8) & 1, n = m >> 9;
    int c = threadIdx.x;
    float zv = f[(size_t)((n * 256 + c) * 2 + d) * 256 + h * 16 + w];
    zrow[c] = zv;
    float s = zv * zv;
    #pragma unroll
    for (int off = 32; off; off >>= 1) s += __shfl_down(s, off, 64);
    if ((c & 63) == 0) red[c >> 6] = s;
    __syncthreads();
    float zn = sqrtf(red[0] + red[1] + red[2] + red[3]);

    for (int k = c; k < K; k += 256) {
        const float4* mr = reinterpret_cast<const float4*>(mem + (size_t)k * 256);
        const float4* zr = reinterpret_cast<const float4*>(zrow);
        float dot = 0.f;
        #pragma unroll 8
        for (int j = 0; j < 64; ++j) {
            float4 mv = mr[j];
            float4 zz = zr[j];
            dot += mv.x * zz.x + mv.y * zz.y + mv.z * zz.z + mv.w * zz.w;
        }
        float den = fmaxf(zn * mnorm[k], 1e-8f);
        scores[(size_t)m * K + k] = dot / den;
    }
}

// ---------------------------------------------------------------------------
// Row softmax over K, in place. One block per row.
// ---------------------------------------------------------------------------
__global__ __launch_bounds__(256) void softmax_k(float* __restrict__ s, int K)
{
    __shared__ float red[4];
    int m = blockIdx.x;
    float* row = s + (size_t)m * K;
    int tid = threadIdx.x;

    float mx = -1e30f;
    for (int k = tid; k < K; k += 256) mx = fmaxf(mx, row[k]);
    #pragma unroll
    for (int off = 32; off; off >>= 1) mx = fmaxf(mx, __shfl_down(mx, off, 64));
    if ((tid & 63) == 0) red[tid >> 6] = mx;
    __syncthreads();
    mx = fmaxf(fmaxf(red[0], red[1]), fmaxf(red[2], red[3]));

    float sm = 0.f;
    for (int k = tid; k < K; k += 256) sm += expf(row[k] - mx);
    #pragma unroll
    for (int off = 32; off; off >>= 1) sm += __shfl_down(sm, off, 64);
    __syncthreads();
    if ((tid & 63) == 0) red[tid >> 6] = sm;
    __syncthreads();
    sm = red[0] + red[1] + red[2] + red[3];
    float inv = 1.0f / sm;
    for (int k = tid; k < K; k += 256) row[k] = expf(row[k] - mx) * inv;
}

// ---------------------------------------------------------------------------
// z_hat = w_hat @ mem, written back to NCDHW layout (zf). One block per m,
// thread c computes channel c.
// ---------------------------------------------------------------------------
__global__ __launch_bounds__(256) void zhat_k(
    const float* __restrict__ w, const float* __restrict__ mem,
    float* __restrict__ zf, int K)
{
    int m = blockIdx.x, c = threadIdx.x;
    const float* wr = w + (size_t)m * K;
    float acc = 0.f;
    #pragma unroll 4
    for (int k = 0; k < K; ++k)
        acc += wr[k] * mem[(size_t)k * 256 + c];
    int ww = m & 15, h = (m >> 4) & 15, d = (m >> 8) & 1, n = m >> 9;
    zf[(size_t)((n * 256 + c) * 2 + d) * 256 + h * 16 + ww] = acc;
}

// ---------------------------------------------------------------------------
// launch
// ---------------------------------------------------------------------------
extern "C" void kernel_launch(void* const* d_in, const int* in_sizes, int n_in,
                              void* d_out, int out_size, void* d_ws, size_t ws_size,
                              hipStream_t stream)
{
    const float* x     = (const float*)d_in[0];
    const float* ew[4] = { (const float*)d_in[1],  (const float*)d_in[5],
                           (const float*)d_in[9],  (const float*)d_in[13] };
    const float* eb[4] = { (const float*)d_in[2],  (const float*)d_in[6],
                           (const float*)d_in[10], (const float*)d_in[14] };
    const float* eg[4] = { (const float*)d_in[3],  (const float*)d_in[7],
                           (const float*)d_in[11], (const float*)d_in[15] };
    const float* ebe[4]= { (const float*)d_in[4],  (const float*)d_in[8],
                           (const float*)d_in[12], (const float*)d_in[16] };
    const float* mem   = (const float*)d_in[17];
    const float* dw[4] = { (const float*)d_in[18], (const float*)d_in[22],
                           (const float*)d_in[26], (const float*)d_in[30] };
    const float* db[4] = { (const float*)d_in[19], (const float*)d_in[23],
                           (const float*)d_in[27], (const float*)d_in[31] };
    const float* dg[3] = { (const float*)d_in[20], (const float*)d_in[24],
                           (const float*)d_in[28] };
    const float* dbe[3]= { (const float*)d_in[21], (const float*)d_in[25],
                           (const float*)d_in[29] };

    float* out   = (float*)d_out;                 // 2*1*16*256*256 = 2,097,152
    float* w_out = (float*)d_out + 2097152;       // 1024*2000 = 2,048,000

    // workspace layout (floats)
    float* ws = (float*)d_ws;
    float* a1    = ws;                 // 50,331,648  (enc1 out; later dec3 out)
    float* a2    = a1 + 50331648;      //  8,388,608  (enc2 out; later dec2 out)
    float* a3    = a2 + 8388608;       //  2,097,152  (enc3 out; later dec1 out)
    float* a4    = a3 + 2097152;       //    262,144  (enc4 out)
    float* zf    = a4 + 262144;        //    262,144  (z_hat in NCDHW)
    float* mnorm = zf + 262144;        //      2,048
    float* meanb = mnorm + 2048;       //        256
    float* varb  = meanb + 256;        //        256

    const int K = 2000;

    // ---------------- encoder ----------------
    // enc1: (2,1,16,256,256) -> (2,96,16,128,128), stride (1,2,2)
    conv3d_k<<<dim3(16 * 128 * 128 / 256, 96, 2), 256, 1 * 27 * 4, stream>>>(
        x, ew[0], eb[0], a1, 1, 16, 256, 256, 16, 128, 128, 1, 2, 2);
    bn_stats_k<<<96, 256, 0, stream>>>(a1, meanb, varb, 96, 16 * 128 * 128, 2);
    bn_lrelu_k<<<2048, 256, 0, stream>>>(a1, meanb, varb, eg[0], ebe[0],
                                         96, 16 * 128 * 128, 2u * 96 * 16 * 128 * 128 / 4);

    // enc2: -> (2,128,8,64,64), stride 2
    conv3d_k<<<dim3(8 * 64 * 64 / 256, 128, 2), 256, 96 * 27 * 4, stream>>>(
        a1, ew[1], eb[1], a2, 96, 16, 128, 128, 8, 64, 64, 2, 2, 2);
    bn_stats_k<<<128, 256, 0, stream>>>(a2, meanb, varb, 128, 8 * 64 * 64, 2);
    bn_lrelu_k<<<2048, 256, 0, stream>>>(a2, meanb, varb, eg[1], ebe[1],
                                         128, 8 * 64 * 64, 2u * 128 * 8 * 64 * 64 / 4);

    // enc3: -> (2,256,4,32,32), stride 2
    conv3d_k<<<dim3(4 * 32 * 32 / 256, 256, 2), 256, 128 * 27 * 4, stream>>>(
        a2, ew[2], eb[2], a3, 128, 8, 64, 64, 4, 32, 32, 2, 2, 2);
    bn_stats_k<<<256, 256, 0, stream>>>(a3, meanb, varb, 256, 4 * 32 * 32, 2);
    bn_lrelu_k<<<2048, 256, 0, stream>>>(a3, meanb, varb, eg[2], ebe[2],
                                         256, 4 * 32 * 32, 2u * 256 * 4 * 32 * 32 / 4);

    // enc4: -> (2,256,2,16,16), stride 2
    conv3d_k<<<dim3(2, 256, 2), 256, 256 * 27 * 4, stream>>>(
        a3, ew[3], eb[3], a4, 256, 4, 32, 32, 2, 16, 16, 2, 2, 2);
    bn_stats_k<<<256, 256, 0, stream>>>(a4, meanb, varb, 256, 2 * 16 * 16, 2);
    bn_lrelu_k<<<512, 256, 0, stream>>>(a4, meanb, varb, eg[3], ebe[3],
                                        256, 2 * 16 * 16, 2u * 256 * 2 * 16 * 16 / 4);

    // ---------------- memory module ----------------
    rownorm_k<<<K, 64, 0, stream>>>(mem, mnorm, 256);
    scores_k<<<1024, 256, 0, stream>>>(a4, mem, mnorm, w_out, K);
    softmax_k<<<1024, 256, 0, stream>>>(w_out, K);
    zhat_k<<<1024, 256, 0, stream>>>(w_out, mem, zf, K);

    // ---------------- decoder ----------------
    // dec1: (2,256,2,16,16) -> (2,256,4,32,32), stride 2, op 1
    convt3d_k<<<dim3(4 * 32 * 32 / 256, 256, 2), 256, 256 * 27 * 4, stream>>>(
        zf, dw[0], db[0], a3, 256, 2, 16, 16, 4, 32, 32, 2, 2, 2);
    bn_stats_k<<<256, 256, 0, stream>>>(a3, meanb, varb, 256, 4 * 32 * 32, 2);
    bn_lrelu_k<<<2048, 256, 0, stream>>>(a3, meanb, varb, dg[0], dbe[0],
                                         256, 4 * 32 * 32, 2u * 256 * 4 * 32 * 32 / 4);

    // dec2: -> (2,128,8,64,64)
    convt3d_k<<<dim3(8 * 64 * 64 / 256, 128, 2), 256, 256 * 27 * 4, stream>>>(
        a3, dw[1], db[1], a2, 256, 4, 32, 32, 8, 64, 64, 2, 2, 2);
    bn_stats_k<<<128, 256, 0, stream>>>(a2, meanb, varb, 128, 8 * 64 * 64, 2);
    bn_lrelu_k<<<2048, 256, 0, stream>>>(a2, meanb, varb, dg[1], dbe[1],
                                         128, 8 * 64 * 64, 2u * 128 * 8 * 64 * 64 / 4);

    // dec3: -> (2,96,16,128,128)
    convt3d_k<<<dim3(16 * 128 * 128 / 256, 96, 2), 256, 128 * 27 * 4, stream>>>(
        a2, dw[2], db[2], a1, 128, 8, 64, 64, 16, 128, 128, 2, 2, 2);
    bn_stats_k<<<96, 256, 0, stream>>>(a1, meanb, varb, 96, 16 * 128 * 128, 2);
    bn_lrelu_k<<<2048, 256, 0, stream>>>(a1, meanb, varb, dg[2], dbe[2],
                                         96, 16 * 128 * 128, 2u * 96 * 16 * 128 * 128 / 4);

    // dec4: -> (2,1,16,256,256), stride (1,2,2), op (0,1,1); no BN
    convt3d_k<<<dim3(16 * 256 * 256 / 256, 1, 2), 256, 96 * 27 * 4, stream>>>(
        a1, dw[3], db[3], out, 96, 16, 128, 128, 16, 256, 256, 1, 2, 2);
}

// Round 2
// 15005.217 us; speedup vs baseline: 1.9520x; 1.9520x over previous
//
#include <hip/hip_runtime.h>
#include <math.h>

#define TD 2
#define TH 8
#define TW 16
#define NS 16

// ---------------------------------------------------------------------------
// Tiled direct Conv3d (k=3, pad=1, runtime stride). Block = (2,8,16) output
// tile x OCH output channels. Input footprint staged in LDS (zero-padded),
// CICH input channels at a time. Weights read via block-uniform indices
// (scalarized to s_load by the compiler).
// grid: (ntiles, Co/OCH, N)
// ---------------------------------------------------------------------------
template<int CICH, int OCH>
__global__ __launch_bounds__(256) void conv_tile_k(
    const float* __restrict__ in, const float* __restrict__ wgt,
    const float* __restrict__ bias, float* __restrict__ out,
    int Ci, int Di, int Hi, int Wi, int Do, int Ho, int Wo,
    int sd, int sh, int sw, int ndy, int ndx)
{
    extern __shared__ float lds[];
    const int tid = threadIdx.x;
    int t = blockIdx.x;
    const int tx_ = t % ndx; t /= ndx;
    const int ty_ = t % ndy; t /= ndy;
    const int z0 = t * TD, y0 = ty_ * TH, x0 = tx_ * TW;
    const int og = blockIdx.y, n = blockIdx.z;
    const int Co = gridDim.y * OCH;

    const int fd = (TD - 1) * sd + 3, fh = (TH - 1) * sh + 3, fw = (TW - 1) * sw + 3;
    const int fhw = fh * fw, ftot = fd * fhw;
    const int gz0 = z0 * sd - 1, gy0 = y0 * sh - 1, gx0 = x0 * sw - 1;
    const int HiWi = Hi * Wi;

    const int txx = tid & 15, tyy = (tid >> 4) & 7, tzz = tid >> 7;
    const int lbase = (tzz * sd) * fhw + (tyy * sh) * fw + txx * sw;

    float acc[OCH];
    #pragma unroll
    for (int o = 0; o < OCH; ++o) acc[o] = 0.f;

    const size_t Ci27 = (size_t)Ci * 27;

    for (int ci0 = 0; ci0 < Ci; ci0 += CICH) {
        __syncthreads();
        for (int i = tid; i < CICH * ftot; i += 256) {
            int ci = i / ftot, r = i - ci * ftot;
            int fz = r / fhw; r -= fz * fhw;
            int fy = r / fw;  int fx = r - fy * fw;
            int zi = gz0 + fz, yi = gy0 + fy, xi = gx0 + fx;
            float v = 0.f;
            if ((unsigned)zi < (unsigned)Di && (unsigned)yi < (unsigned)Hi &&
                (unsigned)xi < (unsigned)Wi)
                v = in[((size_t)(n * Ci + ci0 + ci) * Di + zi) * HiWi + yi * Wi + xi];
            lds[i] = v;
        }
        __syncthreads();
        for (int ci = 0; ci < CICH; ++ci) {
            const float* lp = lds + ci * ftot + lbase;
            float iv[27];
            #pragma unroll
            for (int kd = 0; kd < 3; ++kd)
                #pragma unroll
                for (int kh = 0; kh < 3; ++kh)
                    #pragma unroll
                    for (int kw = 0; kw < 3; ++kw)
                        iv[kd * 9 + kh * 3 + kw] = lp[kd * fhw + kh * fw + kw];
            const float* wb = wgt + (size_t)(og * OCH) * Ci27 + (size_t)(ci0 + ci) * 27;
            #pragma unroll
            for (int o = 0; o < OCH; ++o) {
                const float* wo = wb + (size_t)o * Ci27;
                #pragma unroll
                for (int tp = 0; tp < 27; ++tp)
                    acc[o] += iv[tp] * wo[tp];
            }
        }
    }
    const int HoWo = Ho * Wo;
    const size_t obase = ((size_t)(n * Co + og * OCH) * Do + (z0 + tzz)) * HoWo
                       + (size_t)(y0 + tyy) * Wo + (x0 + txx);
    #pragma unroll
    for (int o = 0; o < OCH; ++o)
        out[obase + (size_t)o * Do * HoWo] = acc[o] + bias[og * OCH + o];
}

// ---------------------------------------------------------------------------
// Tiled ConvTranspose3d, one parity class per launch (compile-time tap sets).
// Output voxel z = (z0c+tz)*SD + PD in full coords; taps and weight indices
// are uniform across the block. Input footprint staged zero-padded in LDS.
// grid: (ntiles_class, Co/OCH, N)
// ---------------------------------------------------------------------------
template<int CICH, int OCH, int SD, int PD, int SH, int PH, int SW, int PW>
__global__ __launch_bounds__(256) void convt_tile_k(
    const float* __restrict__ in, const float* __restrict__ wgt,
    const float* __restrict__ bias, float* __restrict__ out,
    int Ci, int Di, int Hi, int Wi, int Do, int Ho, int Wo,
    int ndy, int ndx)
{
    constexpr int NTD = (SD == 1) ? 3 : (PD == 0 ? 1 : 2);
    constexpr int NTH = (SH == 1) ? 3 : (PH == 0 ? 1 : 2);
    constexpr int NTW = (SW == 1) ? 3 : (PW == 0 ? 1 : 2);
    constexpr int FD = (SD == 1) ? TD + 2 : TD + PD;
    constexpr int FH = (SH == 1) ? TH + 2 : TH + PH;
    constexpr int FW = (SW == 1) ? TW + 2 : TW + PW;
    constexpr int FHW = FH * FW, FTOT = FD * FHW;

    extern __shared__ float lds[];
    const int tid = threadIdx.x;
    int t = blockIdx.x;
    const int tx_ = t % ndx; t /= ndx;
    const int ty_ = t % ndy; t /= ndy;
    const int z0 = t * TD, y0 = ty_ * TH, x0 = tx_ * TW;   // class-space origins
    const int og = blockIdx.y, n = blockIdx.z;
    const int Co = gridDim.y * OCH;

    const int gz0 = (SD == 1) ? z0 - 1 : z0;
    const int gy0 = (SH == 1) ? y0 - 1 : y0;
    const int gx0 = (SW == 1) ? x0 - 1 : x0;
    const int HiWi = Hi * Wi;

    const int txx = tid & 15, tyy = (tid >> 4) & 7, tzz = tid >> 7;
    const int lbase = tzz * FHW + tyy * FW + txx;

    float acc[OCH];
    #pragma unroll
    for (int o = 0; o < OCH; ++o) acc[o] = 0.f;

    const size_t Ci27 = (size_t)Ci * 27;

    for (int ci0 = 0; ci0 < Ci; ci0 += CICH) {
        __syncthreads();
        for (int i = tid; i < CICH * FTOT; i += 256) {
            int ci = i / FTOT, r = i - ci * FTOT;
            int fz = r / FHW; r -= fz * FHW;
            int fy = r / FW;  int fx = r - fy * FW;
            int zi = gz0 + fz, yi = gy0 + fy, xi = gx0 + fx;
            float v = 0.f;
            if ((unsigned)zi < (unsigned)Di && (unsigned)yi < (unsigned)Hi &&
                (unsigned)xi < (unsigned)Wi)
                v = in[((size_t)(n * Ci + ci0 + ci) * Di + zi) * HiWi + yi * Wi + xi];
            lds[i] = v;
        }
        __syncthreads();
        for (int ci = 0; ci < CICH; ++ci) {
            const float* lp = lds + ci * FTOT + lbase;
            float iv[NTD * NTH * NTW];
            #pragma unroll
            for (int jd = 0; jd < NTD; ++jd) {
                int od = (SD == 1) ? jd : ((PD == 0) ? 0 : jd);
                #pragma unroll
                for (int jh = 0; jh < NTH; ++jh) {
                    int oh = (SH == 1) ? jh : ((PH == 0) ? 0 : jh);
                    #pragma unroll
                    for (int jw = 0; jw < NTW; ++jw) {
                        int ow = (SW == 1) ? jw : ((PW == 0) ? 0 : jw);
                        iv[(jd * NTH + jh) * NTW + jw] = lp[od * FHW + oh * FW + ow];
                    }
                }
            }
            const float* wb = wgt + (size_t)(og * OCH) * Ci27 + (size_t)(ci0 + ci) * 27;
            #pragma unroll
            for (int o = 0; o < OCH; ++o) {
                const float* wo = wb + (size_t)o * Ci27;
                #pragma unroll
                for (int jd = 0; jd < NTD; ++jd) {
                    int wd = (SD == 1) ? (2 - jd) : ((PD == 0) ? 1 : ((jd == 0) ? 2 : 0));
                    #pragma unroll
                    for (int jh = 0; jh < NTH; ++jh) {
                        int wh = (SH == 1) ? (2 - jh) : ((PH == 0) ? 1 : ((jh == 0) ? 2 : 0));
                        #pragma unroll
                        for (int jw = 0; jw < NTW; ++jw) {
                            int ww = (SW == 1) ? (2 - jw) : ((PW == 0) ? 1 : ((jw == 0) ? 2 : 0));
                            acc[o] += iv[(jd * NTH + jh) * NTW + jw] * wo[wd * 9 + wh * 3 + ww];
                        }
                    }
                }
            }
        }
    }
    const int HoWo = Ho * Wo;
    const int zo = (z0 + tzz) * SD + PD;
    const int yo = (y0 + tyy) * SH + PH;
    const int xo = (x0 + txx) * SW + PW;
    const size_t obase = ((size_t)(n * Co + og * OCH) * Do + zo) * HoWo
                       + (size_t)yo * Wo + xo;
    #pragma unroll
    for (int o = 0; o < OCH; ++o)
        out[obase + (size_t)o * Do * HoWo] = acc[o] + bias[og * OCH + o];
}

// ---------------------------------------------------------------------------
// BatchNorm batch statistics, sliced: grid (C, NS) partials, then finalize.
// ---------------------------------------------------------------------------
__global__ __launch_bounds__(256) void bn_stats_part_k(
    const float* __restrict__ in, float* __restrict__ pm, float* __restrict__ pv,
    int C, int DHW)
{
    const int c = blockIdx.x, s = blockIdx.y;
    const int T = 2 * DHW;
    const int L = (T + NS - 1) / NS;
    const int e0 = s * L;
    const int e1 = (e0 + L < T) ? e0 + L : T;
    float sm = 0.f, s2 = 0.f;
    for (int e = e0 + threadIdx.x; e < e1; e += 256) {
        int nn = e >= DHW;
        int i = e - nn * DHW;
        float v = in[(size_t)(nn * C + c) * DHW + i];
        sm += v; s2 += v * v;
    }
    #pragma unroll
    for (int off = 32; off; off >>= 1) {
        sm += __shfl_down(sm, off, 64);
        s2 += __shfl_down(s2, off, 64);
    }
    __shared__ float sh[4], sh2[4];
    int wid = threadIdx.x >> 6, lane = threadIdx.x & 63;
    if (lane == 0) { sh[wid] = sm; sh2[wid] = s2; }
    __syncthreads();
    if (threadIdx.x == 0) {
        pm[c * NS + s] = sh[0] + sh[1] + sh[2] + sh[3];
        pv[c * NS + s] = sh2[0] + sh2[1] + sh2[2] + sh2[3];
    }
}

__global__ __launch_bounds__(256) void bn_fin_k(
    const float* __restrict__ pm, const float* __restrict__ pv,
    float* __restrict__ mean, float* __restrict__ var, int C, float invcnt)
{
    int c = threadIdx.x;
    if (c >= C) return;
    float S = 0.f, S2 = 0.f;
    #pragma unroll
    for (int s = 0; s < NS; ++s) { S += pm[c * NS + s]; S2 += pv[c * NS + s]; }
    float m = S * invcnt;
    mean[c] = m;
    var[c] = S2 * invcnt - m * m;
}

// ---------------------------------------------------------------------------
// BN apply + LeakyReLU(0.2), in place, float4 vectorized.
// ---------------------------------------------------------------------------
__global__ __launch_bounds__(256) void bn_lrelu_k(
    float* __restrict__ buf, const float* __restrict__ mean, const float* __restrict__ var,
    const float* __restrict__ g, const float* __restrict__ b,
    int C, int DHW, unsigned int total4)
{
    unsigned int i = blockIdx.x * blockDim.x + threadIdx.x;
    unsigned int stride = gridDim.x * blockDim.x;
    for (; i < total4; i += stride) {
        unsigned int e = i * 4u;
        int c = (int)((e / (unsigned)DHW) % (unsigned)C);
        float m = mean[c], vv = var[c];
        float sc = g[c] * rsqrtf(vv + 1e-5f);
        float sb = b[c] - m * sc;
        float4 v = reinterpret_cast<float4*>(buf)[i];
        v.x = v.x * sc + sb; v.x = v.x >= 0.f ? v.x : 0.2f * v.x;
        v.y = v.y * sc + sb; v.y = v.y >= 0.f ? v.y : 0.2f * v.y;
        v.z = v.z * sc + sb; v.z = v.z >= 0.f ? v.z : 0.2f * v.z;
        v.w = v.w * sc + sb; v.w = v.w >= 0.f ? v.w : 0.2f * v.w;
        reinterpret_cast<float4*>(buf)[i] = v;
    }
}

// ---------------------------------------------------------------------------
// Memory module (unchanged from round 1, correctness-verified)
// ---------------------------------------------------------------------------
__global__ __launch_bounds__(64) void rownorm_k(
    const float* __restrict__ mem, float* __restrict__ nrm, int C)
{
    int k = blockIdx.x;
    const float* p = mem + (size_t)k * C;
    float s = 0.f;
    for (int i = threadIdx.x; i < C; i += 64) { float v = p[i]; s += v * v; }
    #pragma unroll
    for (int off = 32; off; off >>= 1) s += __shfl_down(s, off, 64);
    if (threadIdx.x == 0) nrm[k] = sqrtf(s);
}

__global__ __launch_bounds__(256) void scores_k(
    const float* __restrict__ f, const float* __restrict__ mem,
    const float* __restrict__ mnorm, float* __restrict__ scores, int K)
{
    __shared__ __align__(16) float zrow[256];
    __shared__ float red[4];
    int m = blockIdx.x;
    int w = m & 15, h = (m >> 4) & 15, d = (m >> 8) & 1, n = m >> 9;
    int c = threadIdx.x;
    float zv = f[(size_t)((n * 256 + c) * 2 + d) * 256 + h * 16 + w];
    zrow[c] = zv;
    float s = zv * zv;
    #pragma unroll
    for (int off = 32; off; off >>= 1) s += __shfl_down(s, off, 64);
    if ((c & 63) == 0) red[c >> 6] = s;
    __syncthreads();
    float zn = sqrtf(red[0] + red[1] + red[2] + red[3]);

    for (int k = c; k < K; k += 256) {
        const float4* mr = reinterpret_cast<const float4*>(mem + (size_t)k * 256);
        const float4* zr = reinterpret_cast<const float4*>(zrow);
        float dot = 0.f;
        #pragma unroll 8
        for (int j = 0; j < 64; ++j) {
            float4 mv = mr[j];
            float4 zz = zr[j];
            dot += mv.x * zz.x + mv.y * zz.y + mv.z * zz.z + mv.w * zz.w;
        }
        float den = fmaxf(zn * mnorm[k], 1e-8f);
        scores[(size_t)m * K + k] = dot / den;
    }
}

__global__ __launch_bounds__(256) void softmax_k(float* __restrict__ s, int K)
{
    __shared__ float red[4];
    int m = blockIdx.x;
    float* row = s + (size_t)m * K;
    int tid = threadIdx.x;

    float mx = -1e30f;
    for (int k = tid; k < K; k += 256) mx = fmaxf(mx, row[k]);
    #pragma unroll
    for (int off = 32; off; off >>= 1) mx = fmaxf(mx, __shfl_down(mx, off, 64));
    if ((tid & 63) == 0) red[tid >> 6] = mx;
    __syncthreads();
    mx = fmaxf(fmaxf(red[0], red[1]), fmaxf(red[2], red[3]));

    float sm = 0.f;
    for (int k = tid; k < K; k += 256) sm += expf(row[k] - mx);
    #pragma unroll
    for (int off = 32; off; off >>= 1) sm += __shfl_down(sm, off, 64);
    __syncthreads();
    if ((tid & 63) == 0) red[tid >> 6] = sm;
    __syncthreads();
    sm = red[0] + red[1] + red[2] + red[3];
    float inv = 1.0f / sm;
    for (int k = tid; k < K; k += 256) row[k] = expf(row[k] - mx) * inv;
}

__global__ __launch_bounds__(256) void zhat_k(
    const float* __restrict__ w, const float* __restrict__ mem,
    float* __restrict__ zf, int K)
{
    int m = blockIdx.x, c = threadIdx.x;
    const float* wr = w + (size_t)m * K;
    float acc = 0.f;
    #pragma unroll 4
    for (int k = 0; k < K; ++k)
        acc += wr[k] * mem[(size_t)k * 256 + c];
    int ww = m & 15, h = (m >> 4) & 15, d = (m >> 8) & 1, n = m >> 9;
    zf[(size_t)((n * 256 + c) * 2 + d) * 256 + h * 16 + ww] = acc;
}

// ---------------------------------------------------------------------------
// host-side launch helpers
// ---------------------------------------------------------------------------
template<int PD, int PH, int PW>
static void launch_ct2(const float* in, const float* wgt, const float* bias, float* out,
                       int Ci, int Co, int Di, int Hi, int Wi, int Do, int Ho, int Wo,
                       hipStream_t stream)
{
    int nz = (Do / 2) / TD, ny = (Ho / 2) / TH, nx = (Wo / 2) / TW;
    dim3 g(nz * ny * nx, Co / 8, 2);
    size_t lds = 8u * (TD + PD) * (TH + PH) * (TW + PW) * 4;
    convt_tile_k<8, 8, 2, PD, 2, PH, 2, PW><<<g, 256, lds, stream>>>(
        in, wgt, bias, out, Ci, Di, Hi, Wi, Do, Ho, Wo, ny, nx);
}

static void ct2_all(const float* in, const float* wgt, const float* bias, float* out,
                    int Ci, int Co, int Di, int Hi, int Wi, int Do, int Ho, int Wo,
                    hipStream_t s)
{
    launch_ct2<0,0,0>(in, wgt, bias, out, Ci, Co, Di, Hi, Wi, Do, Ho, Wo, s);
    launch_ct2<0,0,1>(in, wgt, bias, out, Ci, Co, Di, Hi, Wi, Do, Ho, Wo, s);
    launch_ct2<0,1,0>(in, wgt, bias, out, Ci, Co, Di, Hi, Wi, Do, Ho, Wo, s);
    launch_ct2<0,1,1>(in, wgt, bias, out, Ci, Co, Di, Hi, Wi, Do, Ho, Wo, s);
    launch_ct2<1,0,0>(in, wgt, bias, out, Ci, Co, Di, Hi, Wi, Do, Ho, Wo, s);
    launch_ct2<1,0,1>(in, wgt, bias, out, Ci, Co, Di, Hi, Wi, Do, Ho, Wo, s);
    launch_ct2<1,1,0>(in, wgt, bias, out, Ci, Co, Di, Hi, Wi, Do, Ho, Wo, s);
    launch_ct2<1,1,1>(in, wgt, bias, out, Ci, Co, Di, Hi, Wi, Do, Ho, Wo, s);
}

template<int PH, int PW>
static void launch_ct4(const float* in, const float* wgt, const float* bias, float* out,
                       hipStream_t stream)
{
    // dec4: (2,96,16,128,128) -> (2,1,16,256,256), stride (1,2,2)
    int nz = 16 / TD, ny = 128 / TH, nx = 128 / TW;   // class dims (16,128,128)
    dim3 g(nz * ny * nx, 1, 2);
    size_t lds = 8u * (TD + 2) * (TH + PH) * (TW + PW) * 4;
    convt_tile_k<8, 1, 1, 0, 2, PH, 2, PW><<<g, 256, lds, stream>>>(
        in, wgt, bias, out, 96, 16, 128, 128, 16, 256, 256, ny, nx);
}

static void bn_all(float* buf, const float* g, const float* b, float* pm, float* pv,
                   float* meanb, float* varb, int C, int DHW, hipStream_t s)
{
    bn_stats_part_k<<<dim3(C, NS), 256, 0, s>>>(buf, pm, pv, C, DHW);
    bn_fin_k<<<1, 256, 0, s>>>(pm, pv, meanb, varb, C, 1.0f / (2.0f * (float)DHW));
    unsigned int total4 = (unsigned int)(2u * (unsigned)C * (unsigned)DHW / 4u);
    unsigned int blocks = (total4 + 255u) / 256u;
    if (blocks > 2048u) blocks = 2048u;
    bn_lrelu_k<<<blocks, 256, 0, s>>>(buf, meanb, varb, g, b, C, DHW, total4);
}

extern "C" void kernel_launch(void* const* d_in, const int* in_sizes, int n_in,
                              void* d_out, int out_size, void* d_ws, size_t ws_size,
                              hipStream_t stream)
{
    const float* x     = (const float*)d_in[0];
    const float* ew[4] = { (const float*)d_in[1],  (const float*)d_in[5],
                           (const float*)d_in[9],  (const float*)d_in[13] };
    const float* eb[4] = { (const float*)d_in[2],  (const float*)d_in[6],
                           (const float*)d_in[10], (const float*)d_in[14] };
    const float* eg[4] = { (const float*)d_in[3],  (const float*)d_in[7],
                           (const float*)d_in[11], (const float*)d_in[15] };
    const float* ebe[4]= { (const float*)d_in[4],  (const float*)d_in[8],
                           (const float*)d_in[12], (const float*)d_in[16] };
    const float* mem   = (const float*)d_in[17];
    const float* dw[4] = { (const float*)d_in[18], (const float*)d_in[22],
                           (const float*)d_in[26], (const float*)d_in[30] };
    const float* db[4] = { (const float*)d_in[19], (const float*)d_in[23],
                           (const float*)d_in[27], (const float*)d_in[31] };
    const float* dg[3] = { (const float*)d_in[20], (const float*)d_in[24],
                           (const float*)d_in[28] };
    const float* dbe[3]= { (const float*)d_in[21], (const float*)d_in[25],
                           (const float*)d_in[29] };

    float* out   = (float*)d_out;
    float* w_out = (float*)d_out + 2097152;

    float* ws = (float*)d_ws;
    float* a1    = ws;                 // 50,331,648
    float* a2    = a1 + 50331648;      //  8,388,608
    float* a3    = a2 + 8388608;       //  2,097,152
    float* a4    = a3 + 2097152;       //    262,144
    float* zf    = a4 + 262144;        //    262,144
    float* mnorm = zf + 262144;        //      2,048
    float* meanb = mnorm + 2048;       //        256
    float* varb  = meanb + 256;        //        256
    float* pm    = varb + 256;         //      4,096
    float* pv    = pm + 4096;          //      4,096

    const int K = 2000;

    // ---------------- encoder ----------------
    // enc1: (2,1,16,256,256) -> (2,96,16,128,128), stride (1,2,2)
    {
        dim3 g(8 * 16 * 8, 96 / 8, 2);
        size_t lds = 1u * 4 * 17 * 33 * 4;
        conv_tile_k<1, 8><<<g, 256, lds, stream>>>(
            x, ew[0], eb[0], a1, 1, 16, 256, 256, 16, 128, 128, 1, 2, 2, 16, 8);
        bn_all(a1, eg[0], ebe[0], pm, pv, meanb, varb, 96, 16 * 128 * 128, stream);
    }
    // enc2: -> (2,128,8,64,64), stride 2
    {
        dim3 g(4 * 8 * 4, 128 / 8, 2);
        size_t lds = 4u * 5 * 17 * 33 * 4;
        conv_tile_k<4, 8><<<g, 256, lds, stream>>>(
            a1, ew[1], eb[1], a2, 96, 16, 128, 128, 8, 64, 64, 2, 2, 2, 8, 4);
        bn_all(a2, eg[1], ebe[1], pm, pv, meanb, varb, 128, 8 * 64 * 64, stream);
    }
    // enc3: -> (2,256,4,32,32), stride 2
    {
        dim3 g(2 * 4 * 2, 256 / 8, 2);
        size_t lds = 4u * 5 * 17 * 33 * 4;
        conv_tile_k<4, 8><<<g, 256, lds, stream>>>(
            a2, ew[2], eb[2], a3, 128, 8, 64, 64, 4, 32, 32, 2, 2, 2, 4, 2);
        bn_all(a3, eg[2], ebe[2], pm, pv, meanb, varb, 256, 4 * 32 * 32, stream);
    }
    // enc4: -> (2,256,2,16,16), stride 2
    {
        dim3 g(1 * 2 * 1, 256 / 4, 2);
        size_t lds = 4u * 5 * 17 * 33 * 4;
        conv_tile_k<4, 4><<<g, 256, lds, stream>>>(
            a3, ew[3], eb[3], a4, 256, 4, 32, 32, 2, 16, 16, 2, 2, 2, 2, 1);
        bn_all(a4, eg[3], ebe[3], pm, pv, meanb, varb, 256, 2 * 16 * 16, stream);
    }

    // ---------------- memory module ----------------
    rownorm_k<<<K, 64, 0, stream>>>(mem, mnorm, 256);
    scores_k<<<1024, 256, 0, stream>>>(a4, mem, mnorm, w_out, K);
    softmax_k<<<1024, 256, 0, stream>>>(w_out, K);
    zhat_k<<<1024, 256, 0, stream>>>(w_out, mem, zf, K);

    // ---------------- decoder ----------------
    // dec1: (2,256,2,16,16) -> (2,256,4,32,32)
    ct2_all(zf, dw[0], db[0], a3, 256, 256, 2, 16, 16, 4, 32, 32, stream);
    bn_all(a3, dg[0], dbe[0], pm, pv, meanb, varb, 256, 4 * 32 * 32, stream);

    // dec2: -> (2,128,8,64,64)
    ct2_all(a3, dw[1], db[1], a2, 256, 128, 4, 32, 32, 8, 64, 64, stream);
    bn_all(a2, dg[1], dbe[1], pm, pv, meanb, varb, 128, 8 * 64 * 64, stream);

    // dec3: -> (2,96,16,128,128)
    ct2_all(a2, dw[2], db[2], a1, 128, 96, 8, 64, 64, 16, 128, 128, stream);
    bn_all(a1, dg[2], dbe[2], pm, pv, meanb, varb, 96, 16 * 128 * 128, stream);

    // dec4: -> (2,1,16,256,256), stride (1,2,2), no BN
    launch_ct4<0,0>(a1, dw[3], db[3], out, stream);
    launch_ct4<0,1>(a1, dw[3], db[3], out, stream);
    launch_ct4<1,0>(a1, dw[3], db[3], out, stream);
    launch_ct4<1,1>(a1, dw[3], db[3], out, stream);
}

// Round 4
// 2252.974 us; speedup vs baseline: 13.0008x; 6.6602x over previous
//
#include <hip/hip_runtime.h>
#include <math.h>

typedef unsigned short u16;
typedef __bf16 bf16;
typedef bf16 bf16x8 __attribute__((ext_vector_type(8)));
typedef float f32x4 __attribute__((ext_vector_type(4)));
typedef u16 u16x8 __attribute__((ext_vector_type(8)));

__device__ inline float b2f(u16 u){ unsigned x = ((unsigned)u) << 16; return __builtin_bit_cast(float, x); }
__device__ inline u16 f2b(float f){ bf16 b = (bf16)f; return __builtin_bit_cast(u16, b); }
__device__ inline f32x4 mfma16(bf16x8 a, bf16x8 b, f32x4 c){
    return __builtin_amdgcn_mfma_f32_16x16x32_bf16(a, b, c, 0, 0, 0);
}
__device__ inline void unp8(uint4 v, float* f){
    f[0]=__builtin_bit_cast(float, v.x<<16); f[1]=__builtin_bit_cast(float, v.x&0xffff0000u);
    f[2]=__builtin_bit_cast(float, v.y<<16); f[3]=__builtin_bit_cast(float, v.y&0xffff0000u);
    f[4]=__builtin_bit_cast(float, v.z<<16); f[5]=__builtin_bit_cast(float, v.z&0xffff0000u);
    f[6]=__builtin_bit_cast(float, v.w<<16); f[7]=__builtin_bit_cast(float, v.w&0xffff0000u);
}

// ---------------------------------------------------------------------------
// Weight repack: OIDHW fp32 -> [tap][co][ci] bf16 (B^T form for MFMA).
// ---------------------------------------------------------------------------
__global__ __launch_bounds__(256) void repack_k(
    const float* __restrict__ w, u16* __restrict__ o, int Co, int Ci)
{
    int tot = 27 * Co * Ci;
    for (int e = blockIdx.x * 256 + threadIdx.x; e < tot; e += gridDim.x * 256) {
        int ci = e % Ci; int t2 = e / Ci; int co = t2 % Co; int tp = t2 / Co;
        o[e] = f2b(w[(size_t)(co * Ci + ci) * 27 + tp]);
    }
}

// ---------------------------------------------------------------------------
// MFMA implicit-GEMM conv3d (stride 2) / convT3d (stride 2, 8 parity classes
// on grid.z). Channels-last bf16 activations, weights [tap][co][ci] bf16.
// Block: 256 thr = 4 waves (2x2), tile BM=64 rows x BN=64 cols, K-chunk 32.
// grid: (M/64, ceil(Co/64), ISCONV?1:8)
// ---------------------------------------------------------------------------
template<bool ISCONV>
__global__ __launch_bounds__(256) void conv_mfma_k(
    const u16* __restrict__ in, const u16* __restrict__ wt,
    const float* __restrict__ bias, u16* __restrict__ out,
    int Ci, int Co, int Di, int Hi, int Wi,
    int ld, int lh, int lw, int Do, int Ho, int Wo)
{
    __shared__ u16 As[64][40];
    __shared__ u16 Bs[64][40];
    const int tid = threadIdx.x;
    const int mtile = blockIdx.x, co0 = blockIdx.y << 6;
    int pd = 0, ph = 0, pw = 0;
    if (!ISCONV) { int bz = blockIdx.z; pd = bz >> 2; ph = (bz >> 1) & 1; pw = bz & 1; }

    const int arow = tid >> 2, seg = tid & 3;
    int xo, yo, zo, n;
    { int m = (mtile << 6) + arow;
      xo = m & ((1 << lw) - 1); m >>= lw;
      yo = m & ((1 << lh) - 1); m >>= lh;
      zo = m & ((1 << ld) - 1); n = m >> ld; }
    const bool brow_ok = (co0 + arow) < Co;

    const int wave = tid >> 6, lane = tid & 63;
    const int wm = wave >> 1, wn = wave & 1, fr = lane & 15, fs = lane >> 4;

    f32x4 acc00 = {0,0,0,0}, acc01 = {0,0,0,0}, acc10 = {0,0,0,0}, acc11 = {0,0,0,0};

    const int ntd = ISCONV ? 3 : pd + 1;
    const int nth = ISCONV ? 3 : ph + 1;
    const int ntw = ISCONV ? 3 : pw + 1;
    const size_t HiWi = (size_t)Hi * Wi;

    for (int jd = 0; jd < ntd; ++jd) {
        int zi = ISCONV ? 2 * zo + jd - 1 : zo + (pd ? jd : 0);
        int wd = ISCONV ? jd : (pd ? (jd ? 0 : 2) : 1);
        bool vz = (unsigned)zi < (unsigned)Di;
        for (int jh = 0; jh < nth; ++jh) {
            int yi = ISCONV ? 2 * yo + jh - 1 : yo + (ph ? jh : 0);
            int wh = ISCONV ? jh : (ph ? (jh ? 0 : 2) : 1);
            bool vy = vz && ((unsigned)yi < (unsigned)Hi);
            for (int jw = 0; jw < ntw; ++jw) {
                int xi = ISCONV ? 2 * xo + jw - 1 : xo + (pw ? jw : 0);
                int ww = ISCONV ? jw : (pw ? (jw ? 0 : 2) : 1);
                bool va = vy && ((unsigned)xi < (unsigned)Wi);
                size_t abase = 0;
                if (va) abase = (((size_t)(n * Di + zi)) * HiWi + (size_t)yi * Wi + xi) * Ci + seg * 8;
                int widx = wd * 9 + wh * 3 + ww;
                size_t bbase = ((size_t)widx * Co + (co0 + arow)) * (size_t)Ci + seg * 8;
                for (int ci0 = 0; ci0 < Ci; ci0 += 32) {
                    uint4 avv = {0,0,0,0}, bvv = {0,0,0,0};
                    if (va)      avv = *reinterpret_cast<const uint4*>(in + abase + ci0);
                    if (brow_ok) bvv = *reinterpret_cast<const uint4*>(wt + bbase + ci0);
                    __syncthreads();
                    *reinterpret_cast<uint4*>(&As[arow][seg * 8]) = avv;
                    *reinterpret_cast<uint4*>(&Bs[arow][seg * 8]) = bvv;
                    __syncthreads();
                    bf16x8 a0 = *reinterpret_cast<const bf16x8*>(&As[wm * 32      + fr][fs * 8]);
                    bf16x8 a1 = *reinterpret_cast<const bf16x8*>(&As[wm * 32 + 16 + fr][fs * 8]);
                    bf16x8 b0 = *reinterpret_cast<const bf16x8*>(&Bs[wn * 32      + fr][fs * 8]);
                    bf16x8 b1 = *reinterpret_cast<const bf16x8*>(&Bs[wn * 32 + 16 + fr][fs * 8]);
                    acc00 = mfma16(a0, b0, acc00);
                    acc01 = mfma16(a0, b1, acc01);
                    acc10 = mfma16(a1, b0, acc10);
                    acc11 = mfma16(a1, b1, acc11);
                }
            }
        }
    }
    // epilogue: C/D layout col=lane&15, row=(lane>>4)*4+j  [m89-verified]
    const int c0 = co0 + wn * 32 + fr;
    const int c1 = c0 + 16;
    float bi0 = (c0 < Co) ? bias[c0] : 0.f;
    float bi1 = (c1 < Co) ? bias[c1] : 0.f;
    #pragma unroll
    for (int mi = 0; mi < 2; ++mi) {
        f32x4 aN0 = mi ? acc10 : acc00;
        f32x4 aN1 = mi ? acc11 : acc01;
        #pragma unroll
        for (int j = 0; j < 4; ++j) {
            int rm = (mtile << 6) + wm * 32 + mi * 16 + fs * 4 + j;
            size_t vox;
            if (ISCONV) vox = (size_t)rm;
            else {
                int X = rm & ((1 << lw) - 1); int m2 = rm >> lw;
                int Y = m2 & ((1 << lh) - 1); m2 >>= lh;
                int Z = m2 & ((1 << ld) - 1); int nn = m2 >> ld;
                vox = (((size_t)(nn * Do + (2 * Z + pd))) * Ho + (2 * Y + ph)) * Wo + (2 * X + pw);
            }
            if (c0 < Co) out[vox * Co + c0] = f2b(aN0[j] + bi0);
            if (c1 < Co) out[vox * Co + c1] = f2b(aN1[j] + bi1);
        }
    }
}

// ---------------------------------------------------------------------------
// enc1: (2,1,16,256,256) fp32 -> (2,16,128,128,96) bf16 CL, stride (1,2,2).
// Tile (2,8,16), 1 thread/voxel, all 96 Co per thread. grid (1024, 2)
// ---------------------------------------------------------------------------
__global__ __launch_bounds__(256) void enc1_k(
    const float* __restrict__ x, const float* __restrict__ w,
    const float* __restrict__ bias, u16* __restrict__ out)
{
    __shared__ float Xi[4 * 17 * 33];
    __shared__ float Wl[96 * 27];
    __shared__ float Bl[96];
    const int tid = threadIdx.x;
    int t = blockIdx.x;
    const int tx = t & 7; t >>= 3;
    const int ty = t & 15; t >>= 4;
    const int tz = t;
    const int n = blockIdx.y;
    const int z0 = tz * 2, y0 = ty * 8, x0 = tx * 16;
    for (int i = tid; i < 2592; i += 256) Wl[i] = w[i];
    for (int i = tid; i < 96; i += 256) Bl[i] = bias[i];
    for (int i = tid; i < 2244; i += 256) {
        int fz = i / 561; int r = i - fz * 561; int fy = r / 33; int fx = r - fy * 33;
        int zi = z0 - 1 + fz, yi = 2 * y0 - 1 + fy, xi = 2 * x0 - 1 + fx;
        float v = 0.f;
        if ((unsigned)zi < 16u && (unsigned)yi < 256u && (unsigned)xi < 256u)
            v = x[((size_t)(n * 16 + zi) * 256 + yi) * 256 + xi];
        Xi[i] = v;
    }
    __syncthreads();
    const int lx = tid & 15, ly = (tid >> 4) & 7, lz = tid >> 7;
    float iv[27];
    #pragma unroll
    for (int kd = 0; kd < 3; ++kd)
        #pragma unroll
        for (int kh = 0; kh < 3; ++kh)
            #pragma unroll
            for (int kw = 0; kw < 3; ++kw)
                iv[kd * 9 + kh * 3 + kw] = Xi[(lz + kd) * 561 + (2 * ly + kh) * 33 + (2 * lx + kw)];
    size_t vox = ((size_t)(n * 16 + z0 + lz) * 128 + (y0 + ly)) * 128 + (x0 + lx);
    u16* op = out + vox * 96;
    #pragma unroll
    for (int og = 0; og < 12; ++og) {
        u16x8 pk;
        #pragma unroll
        for (int oo = 0; oo < 8; ++oo) {
            int o = og * 8 + oo;
            float a = Bl[o];
            #pragma unroll
            for (int tp = 0; tp < 27; ++tp) a += iv[tp] * Wl[o * 27 + tp];
            pk[oo] = f2b(a);
        }
        *reinterpret_cast<u16x8*>(op + og * 8) = pk;
    }
}

// ---------------------------------------------------------------------------
// dec4: (2,16,128,128,96) bf16 CL -> (2,1,16,256,256) fp32, stride (1,2,2),
// per (PH,PW) class. Tile (2,8,16) in class space. grid (1024, 2)
// ---------------------------------------------------------------------------
template<int PH, int PW>
__global__ __launch_bounds__(256) void dec4_k(
    const u16* __restrict__ in, const float* __restrict__ w,
    const float* __restrict__ bias, float* __restrict__ out)
{
    constexpr int FH = 8 + PH, FW = 16 + PW, FHW = FH * FW, FTOT = 4 * FHW;
    __shared__ u16 Ai[FTOT][32];
    __shared__ float Wl[96 * 27];
    const int tid = threadIdx.x;
    int t = blockIdx.x;
    const int tx = t & 7; t >>= 3;
    const int ty = t & 15; t >>= 4;
    const int tz = t;
    const int n = blockIdx.y;
    const int z0 = tz * 2, y0 = ty * 8, x0 = tx * 16;
    for (int i = tid; i < 2592; i += 256) Wl[i] = w[i];
    const int lx = tid & 15, ly = (tid >> 4) & 7, lz = tid >> 7;
    float acc = bias[0];
    for (int ci0 = 0; ci0 < 96; ci0 += 32) {
        __syncthreads();
        for (int i = tid; i < FTOT * 4; i += 256) {
            int v = i >> 2, sg = i & 3;
            int fz = v / FHW; int r = v - fz * FHW; int fy = r / FW; int fx = r - fy * FW;
            int zi = z0 - 1 + fz, yi = y0 + fy, xi = x0 + fx;
            uint4 vv = {0,0,0,0};
            if ((unsigned)zi < 16u && (unsigned)yi < 128u && (unsigned)xi < 128u)
                vv = *reinterpret_cast<const uint4*>(
                    in + (((size_t)(n * 16 + zi) * 128 + yi) * 128 + xi) * 96 + ci0 + sg * 8);
            *reinterpret_cast<uint4*>(&Ai[v][sg * 8]) = vv;
        }
        __syncthreads();
        #pragma unroll
        for (int jd = 0; jd < 3; ++jd) {
            #pragma unroll
            for (int jh = 0; jh <= PH; ++jh) {
                #pragma unroll
                for (int jw = 0; jw <= PW; ++jw) {
                    int v = (lz + jd) * FHW + (ly + jh) * FW + (lx + jw);
                    int wd = 2 - jd;
                    int wh = PH ? (jh ? 0 : 2) : 1;
                    int ww = PW ? (jw ? 0 : 2) : 1;
                    int wtap = wd * 9 + wh * 3 + ww;
                    const u16* ap = &Ai[v][0];
                    #pragma unroll
                    for (int c8 = 0; c8 < 4; ++c8) {
                        bf16x8 iv8 = *reinterpret_cast<const bf16x8*>(ap + c8 * 8);
                        #pragma unroll
                        for (int e = 0; e < 8; ++e)
                            acc += (float)iv8[e] * Wl[(ci0 + c8 * 8 + e) * 27 + wtap];
                    }
                }
            }
        }
    }
    const int Z = z0 + lz, Y = 2 * (y0 + ly) + PH, X = 2 * (x0 + lx) + PW;
    out[((size_t)(n * 16 + Z) * 256 + Y) * 256 + X] = acc;
}

// ---------------------------------------------------------------------------
// BN stats, fully deterministic: per-thread 8-slot partials -> LDS ->
// fixed-order per-channel gather using the congruence
// channel(t,e) = (blockIdx*2048 + t*8 + e) mod C  (C divisible by 8).
// Per-thread slot-channel is invariant under the grid stride because
// gridDim*2048 % C == 0 for every (grid, C) we launch.
// ---------------------------------------------------------------------------
__global__ __launch_bounds__(256) void bnstat_k(
    const u16* __restrict__ a, float* __restrict__ pm, float* __restrict__ pv,
    int C, unsigned total8)
{
    __shared__ float sS[256][8];
    __shared__ float sQ[256][8];
    unsigned g = blockIdx.x * 256 + threadIdx.x;
    unsigned stride = gridDim.x * 256;
    float s[8] = {0,0,0,0,0,0,0,0}, q[8] = {0,0,0,0,0,0,0,0};
    for (unsigned i = g; i < total8; i += stride) {
        uint4 v = *reinterpret_cast<const uint4*>(a + (size_t)i * 8);
        float f[8]; unp8(v, f);
        #pragma unroll
        for (int e = 0; e < 8; ++e) { s[e] += f[e]; q[e] += f[e] * f[e]; }
    }
    #pragma unroll
    for (int e = 0; e < 8; ++e) { sS[threadIdx.x][e] = s[e]; sQ[threadIdx.x][e] = q[e]; }
    __syncthreads();
    int c = threadIdx.x;
    if (c < C) {
        int C8 = C >> 3;
        int B = (int)((blockIdx.x * 2048u) % (unsigned)C);
        int r = c - B; r %= C; if (r < 0) r += C;
        int e = r & 7, t0 = r >> 3;
        float S = 0.f, Q = 0.f;
        for (int tt = t0; tt < 256; tt += C8) { S += sS[tt][e]; Q += sQ[tt][e]; }
        pm[blockIdx.x * C + c] = S;
        pv[blockIdx.x * C + c] = Q;
    }
}

__global__ __launch_bounds__(256) void bnfin_k(
    const float* __restrict__ pm, const float* __restrict__ pv,
    const float* __restrict__ g, const float* __restrict__ be,
    float* __restrict__ sc, float* __restrict__ sb, int C, int G, float invcnt)
{
    int c = threadIdx.x;
    if (c >= C) return;
    float S = 0.f, Q = 0.f;
    for (int b = 0; b < G; ++b) { S += pm[b * C + c]; Q += pv[b * C + c]; }
    float m = S * invcnt;
    float v = Q * invcnt - m * m;
    float s = g[c] * rsqrtf(v + 1e-5f);
    sc[c] = s; sb[c] = be[c] - m * s;
}

__global__ __launch_bounds__(256) void bnapply_k(
    u16* __restrict__ a, const float* __restrict__ sc, const float* __restrict__ sb,
    int C, unsigned total8)
{
    unsigned g = blockIdx.x * 256 + threadIdx.x;
    unsigned stride = gridDim.x * 256;
    int c0 = (int)((g * 8u) % (unsigned)C);
    float lsc[8], lsb[8];
    #pragma unroll
    for (int e = 0; e < 8; ++e) { lsc[e] = sc[c0 + e]; lsb[e] = sb[c0 + e]; }
    for (unsigned i = g; i < total8; i += stride) {
        uint4 v = *reinterpret_cast<const uint4*>(a + (size_t)i * 8);
        float f[8]; unp8(v, f);
        u16x8 pk;
        #pragma unroll
        for (int e = 0; e < 8; ++e) {
            float y = f[e] * lsc[e] + lsb[e];
            y = y >= 0.f ? y : 0.2f * y;
            pk[e] = f2b(y);
        }
        *reinterpret_cast<u16x8*>(a + (size_t)i * 8) = pk;
    }
}

// ---------------------------------------------------------------------------
// Memory module (channels-last bf16 z; fp32 mem/scores)
// ---------------------------------------------------------------------------
__global__ __launch_bounds__(64) void rownorm_k(
    const float* __restrict__ mem, float* __restrict__ nrm, int C)
{
    int k = blockIdx.x;
    const float* p = mem + (size_t)k * C;
    float s = 0.f;
    for (int i = threadIdx.x; i < C; i += 64) { float v = p[i]; s += v * v; }
    #pragma unroll
    for (int off = 32; off; off >>= 1) s += __shfl_down(s, off, 64);
    if (threadIdx.x == 0) nrm[k] = sqrtf(s);
}

__global__ __launch_bounds__(256) void scores_k(
    const u16* __restrict__ zin, const float* __restrict__ mem,
    const float* __restrict__ mnorm, float* __restrict__ scores, int K)
{
    __shared__ __align__(16) float zrow[256];
    __shared__ float red[4];
    int m = blockIdx.x;
    int c = threadIdx.x;
    float zv = b2f(zin[(size_t)m * 256 + c]);
    zrow[c] = zv;
    float s = zv * zv;
    #pragma unroll
    for (int off = 32; off; off >>= 1) s += __shfl_down(s, off, 64);
    if ((c & 63) == 0) red[c >> 6] = s;
    __syncthreads();
    float zn = sqrtf(red[0] + red[1] + red[2] + red[3]);

    for (int k = c; k < K; k += 256) {
        const float4* mr = reinterpret_cast<const float4*>(mem + (size_t)k * 256);
        const float4* zr = reinterpret_cast<const float4*>(zrow);
        float dot = 0.f;
        #pragma unroll 8
        for (int j = 0; j < 64; ++j) {
            float4 mv = mr[j];
            float4 zz = zr[j];
            dot += mv.x * zz.x + mv.y * zz.y + mv.z * zz.z + mv.w * zz.w;
        }
        float den = fmaxf(zn * mnorm[k], 1e-8f);
        scores[(size_t)m * K + k] = dot / den;
    }
}

__global__ __launch_bounds__(256) void softmax_k(float* __restrict__ s, int K)
{
    __shared__ float red[4];
    int m = blockIdx.x;
    float* row = s + (size_t)m * K;
    int tid = threadIdx.x;

    float mx = -1e30f;
    for (int k = tid; k < K; k += 256) mx = fmaxf(mx, row[k]);
    #pragma unroll
    for (int off = 32; off; off >>= 1) mx = fmaxf(mx, __shfl_down(mx, off, 64));
    if ((tid & 63) == 0) red[tid >> 6] = mx;
    __syncthreads();
    mx = fmaxf(fmaxf(red[0], red[1]), fmaxf(red[2], red[3]));

    float sm = 0.f;
    for (int k = tid; k < K; k += 256) sm += expf(row[k] - mx);
    #pragma unroll
    for (int off = 32; off; off >>= 1) sm += __shfl_down(sm, off, 64);
    __syncthreads();
    if ((tid & 63) == 0) red[tid >> 6] = sm;
    __syncthreads();
    sm = red[0] + red[1] + red[2] + red[3];
    float inv = 1.0f / sm;
    for (int k = tid; k < K; k += 256) row[k] = expf(row[k] - mx) * inv;
}

__global__ __launch_bounds__(256) void zhat_k(
    const float* __restrict__ w, const float* __restrict__ mem,
    u16* __restrict__ zf, int K)
{
    int m = blockIdx.x, c = threadIdx.x;
    const float* wr = w + (size_t)m * K;
    float acc = 0.f;
    #pragma unroll 4
    for (int k = 0; k < K; ++k)
        acc += wr[k] * mem[(size_t)k * 256 + c];
    zf[(size_t)m * 256 + c] = f2b(acc);
}

// ---------------------------------------------------------------------------
// launch
// ---------------------------------------------------------------------------
extern "C" void kernel_launch(void* const* d_in, const int* in_sizes, int n_in,
                              void* d_out, int out_size, void* d_ws, size_t ws_size,
                              hipStream_t stream)
{
    const float* x     = (const float*)d_in[0];
    const float* ew[4] = { (const float*)d_in[1],  (const float*)d_in[5],
                           (const float*)d_in[9],  (const float*)d_in[13] };
    const float* eb[4] = { (const float*)d_in[2],  (const float*)d_in[6],
                           (const float*)d_in[10], (const float*)d_in[14] };
    const float* eg[4] = { (const float*)d_in[3],  (const float*)d_in[7],
                           (const float*)d_in[11], (const float*)d_in[15] };
    const float* ebe[4]= { (const float*)d_in[4],  (const float*)d_in[8],
                           (const float*)d_in[12], (const float*)d_in[16] };
    const float* mem   = (const float*)d_in[17];
    const float* dw[4] = { (const float*)d_in[18], (const float*)d_in[22],
                           (const float*)d_in[26], (const float*)d_in[30] };
    const float* db[4] = { (const float*)d_in[19], (const float*)d_in[23],
                           (const float*)d_in[27], (const float*)d_in[31] };
    const float* dg[3] = { (const float*)d_in[20], (const float*)d_in[24],
                           (const float*)d_in[28] };
    const float* dbe[3]= { (const float*)d_in[21], (const float*)d_in[25],
                           (const float*)d_in[29] };

    float* outp  = (float*)d_out;
    float* w_out = (float*)d_out + 2097152;

    char* p = (char*)d_ws;
    auto take = [&](size_t bytes) -> char* {
        char* q = p; p += (bytes + 255) & ~(size_t)255; return q;
    };
    u16* b1   = (u16*)take(50331648ull * 2);
    u16* b2   = (u16*)take(8388608ull * 2);
    u16* b3   = (u16*)take(2097152ull * 2);
    u16* b4   = (u16*)take(262144ull * 2);
    u16* zf   = (u16*)take(262144ull * 2);
    u16* w2   = (u16*)take(331776ull * 2);
    u16* w3   = (u16*)take(884736ull * 2);
    u16* w4   = (u16*)take(1769472ull * 2);
    u16* wd1  = (u16*)take(1769472ull * 2);
    u16* wd2  = (u16*)take(884736ull * 2);
    u16* wd3  = (u16*)take(331776ull * 2);
    float* pm    = (float*)take(131072 * 4);
    float* pv    = (float*)take(131072 * 4);
    float* scb   = (float*)take(512 * 4);
    float* mnorm = (float*)take(2048 * 4);

    const int K = 2000;

    auto bn = [&](u16* buf, const float* g, const float* be, int C, unsigned total8, int G) {
        bnstat_k<<<G, 256, 0, stream>>>(buf, pm, pv, C, total8);
        bnfin_k<<<1, 256, 0, stream>>>(pm, pv, g, be, scb, scb + 256, C, G,
                                       (float)C / ((float)total8 * 8.0f));
        bnapply_k<<<G, 256, 0, stream>>>(buf, scb, scb + 256, C, total8);
    };

    // ---- weight repacks ----
    repack_k<<<256, 256, 0, stream>>>(ew[1], w2, 128, 96);
    repack_k<<<256, 256, 0, stream>>>(ew[2], w3, 256, 128);
    repack_k<<<256, 256, 0, stream>>>(ew[3], w4, 256, 256);
    repack_k<<<256, 256, 0, stream>>>(dw[0], wd1, 256, 256);
    repack_k<<<256, 256, 0, stream>>>(dw[1], wd2, 128, 256);
    repack_k<<<256, 256, 0, stream>>>(dw[2], wd3, 96, 128);

    // ---- encoder ----
    enc1_k<<<dim3(1024, 2), 256, 0, stream>>>(x, ew[0], eb[0], b1);
    bn(b1, eg[0], ebe[0], 96, 6291456u, 768);

    conv_mfma_k<true><<<dim3(1024, 2, 1), 256, 0, stream>>>(
        b1, w2, eb[1], b2, 96, 128, 16, 128, 128, 3, 6, 6, 8, 64, 64);
    bn(b2, eg[1], ebe[1], 128, 1048576u, 512);

    conv_mfma_k<true><<<dim3(128, 4, 1), 256, 0, stream>>>(
        b2, w3, eb[2], b3, 128, 256, 8, 64, 64, 2, 5, 5, 4, 32, 32);
    bn(b3, eg[2], ebe[2], 256, 262144u, 512);

    conv_mfma_k<true><<<dim3(16, 4, 1), 256, 0, stream>>>(
        b3, w4, eb[3], b4, 256, 256, 4, 32, 32, 1, 4, 4, 2, 16, 16);
    bn(b4, eg[3], ebe[3], 256, 32768u, 128);

    // ---- memory module ----
    rownorm_k<<<K, 64, 0, stream>>>(mem, mnorm, 256);
    scores_k<<<1024, 256, 0, stream>>>(b4, mem, mnorm, w_out, K);
    softmax_k<<<1024, 256, 0, stream>>>(w_out, K);
    zhat_k<<<1024, 256, 0, stream>>>(w_out, mem, zf, K);

    // ---- decoder ----
    conv_mfma_k<false><<<dim3(16, 4, 8), 256, 0, stream>>>(
        zf, wd1, db[0], b3, 256, 256, 2, 16, 16, 1, 4, 4, 4, 32, 32);
    bn(b3, dg[0], dbe[0], 256, 262144u, 512);

    conv_mfma_k<false><<<dim3(128, 2, 8), 256, 0, stream>>>(
        b3, wd2, db[1], b2, 256, 128, 4, 32, 32, 2, 5, 5, 8, 64, 64);
    bn(b2, dg[1], dbe[1], 128, 1048576u, 512);

    conv_mfma_k<false><<<dim3(1024, 2, 8), 256, 0, stream>>>(
        b2, wd3, db[2], b1, 128, 96, 8, 64, 64, 3, 6, 6, 16, 128, 128);
    bn(b1, dg[2], dbe[2], 96, 6291456u, 768);

    dec4_k<0,0><<<dim3(1024, 2), 256, 0, stream>>>(b1, dw[3], db[3], outp);
    dec4_k<0,1><<<dim3(1024, 2), 256, 0, stream>>>(b1, dw[3], db[3], outp);
    dec4_k<1,0><<<dim3(1024, 2), 256, 0, stream>>>(b1, dw[3], db[3], outp);
    dec4_k<1,1><<<dim3(1024, 2), 256, 0, stream>>>(b1, dw[3], db[3], outp);
}

// Round 6
// 1084.710 us; speedup vs baseline: 27.0031x; 2.0770x over previous
//
#include <hip/hip_runtime.h>
#include <math.h>

typedef unsigned short u16;
typedef __bf16 bf16;
typedef bf16 bf16x8 __attribute__((ext_vector_type(8)));
typedef float f32x4 __attribute__((ext_vector_type(4)));
typedef u16 u16x8 __attribute__((ext_vector_type(8)));

__device__ inline float b2f(u16 u){ unsigned x = ((unsigned)u) << 16; return __builtin_bit_cast(float, x); }
__device__ inline u16 f2b(float f){ bf16 b = (bf16)f; return __builtin_bit_cast(u16, b); }
__device__ inline f32x4 mfma16(bf16x8 a, bf16x8 b, f32x4 c){
    return __builtin_amdgcn_mfma_f32_16x16x32_bf16(a, b, c, 0, 0, 0);
}
__device__ inline void unp8(uint4 v, float* f){
    f[0]=__builtin_bit_cast(float, v.x<<16); f[1]=__builtin_bit_cast(float, v.x&0xffff0000u);
    f[2]=__builtin_bit_cast(float, v.y<<16); f[3]=__builtin_bit_cast(float, v.y&0xffff0000u);
    f[4]=__builtin_bit_cast(float, v.z<<16); f[5]=__builtin_bit_cast(float, v.z&0xffff0000u);
    f[6]=__builtin_bit_cast(float, v.w<<16); f[7]=__builtin_bit_cast(float, v.w&0xffff0000u);
}

// ---------------------------------------------------------------------------
// Weight repack: OIDHW fp32 -> [tap][co][ci] bf16 (B^T form for MFMA).
// ---------------------------------------------------------------------------
__global__ __launch_bounds__(256) void repack_k(
    const float* __restrict__ w, u16* __restrict__ o, int Co, int Ci)
{
    int tot = 27 * Co * Ci;
    for (int e = blockIdx.x * 256 + threadIdx.x; e < tot; e += gridDim.x * 256) {
        int ci = e % Ci; int t2 = e / Ci; int co = t2 % Co; int tp = t2 / Co;
        o[e] = f2b(w[(size_t)(co * Ci + ci) * 27 + tp]);
    }
}

// ---------------------------------------------------------------------------
// MFMA implicit-GEMM conv3d (stride 2) / convT3d (stride 2, 8 parity classes
// on grid.z). Channels-last bf16 activations, weights [tap][co][ci] bf16.
// ---------------------------------------------------------------------------
template<bool ISCONV>
__global__ __launch_bounds__(256) void conv_mfma_k(
    const u16* __restrict__ in, const u16* __restrict__ wt,
    const float* __restrict__ bias, u16* __restrict__ out,
    int Ci, int Co, int Di, int Hi, int Wi,
    int ld, int lh, int lw, int Do, int Ho, int Wo)
{
    __shared__ u16 As[64][40];
    __shared__ u16 Bs[64][40];
    const int tid = threadIdx.x;
    const int mtile = blockIdx.x, co0 = blockIdx.y << 6;
    int pd = 0, ph = 0, pw = 0;
    if (!ISCONV) { int bz = blockIdx.z; pd = bz >> 2; ph = (bz >> 1) & 1; pw = bz & 1; }

    const int arow = tid >> 2, seg = tid & 3;
    int xo, yo, zo, n;
    { int m = (mtile << 6) + arow;
      xo = m & ((1 << lw) - 1); m >>= lw;
      yo = m & ((1 << lh) - 1); m >>= lh;
      zo = m & ((1 << ld) - 1); n = m >> ld; }
    const bool brow_ok = (co0 + arow) < Co;

    const int wave = tid >> 6, lane = tid & 63;
    const int wm = wave >> 1, wn = wave & 1, fr = lane & 15, fs = lane >> 4;

    f32x4 acc00 = {0,0,0,0}, acc01 = {0,0,0,0}, acc10 = {0,0,0,0}, acc11 = {0,0,0,0};

    const int ntd = ISCONV ? 3 : pd + 1;
    const int nth = ISCONV ? 3 : ph + 1;
    const int ntw = ISCONV ? 3 : pw + 1;
    const size_t HiWi = (size_t)Hi * Wi;

    for (int jd = 0; jd < ntd; ++jd) {
        int zi = ISCONV ? 2 * zo + jd - 1 : zo + (pd ? jd : 0);
        int wd = ISCONV ? jd : (pd ? (jd ? 0 : 2) : 1);
        bool vz = (unsigned)zi < (unsigned)Di;
        for (int jh = 0; jh < nth; ++jh) {
            int yi = ISCONV ? 2 * yo + jh - 1 : yo + (ph ? jh : 0);
            int wh = ISCONV ? jh : (ph ? (jh ? 0 : 2) : 1);
            bool vy = vz && ((unsigned)yi < (unsigned)Hi);
            for (int jw = 0; jw < ntw; ++jw) {
                int xi = ISCONV ? 2 * xo + jw - 1 : xo + (pw ? jw : 0);
                int ww = ISCONV ? jw : (pw ? (jw ? 0 : 2) : 1);
                bool va = vy && ((unsigned)xi < (unsigned)Wi);
                size_t abase = 0;
                if (va) abase = (((size_t)(n * Di + zi)) * HiWi + (size_t)yi * Wi + xi) * Ci + seg * 8;
                int widx = wd * 9 + wh * 3 + ww;
                size_t bbase = ((size_t)widx * Co + (co0 + arow)) * (size_t)Ci + seg * 8;
                for (int ci0 = 0; ci0 < Ci; ci0 += 32) {
                    uint4 avv = {0,0,0,0}, bvv = {0,0,0,0};
                    if (va)      avv = *reinterpret_cast<const uint4*>(in + abase + ci0);
                    if (brow_ok) bvv = *reinterpret_cast<const uint4*>(wt + bbase + ci0);
                    __syncthreads();
                    *reinterpret_cast<uint4*>(&As[arow][seg * 8]) = avv;
                    *reinterpret_cast<uint4*>(&Bs[arow][seg * 8]) = bvv;
                    __syncthreads();
                    bf16x8 a0 = *reinterpret_cast<const bf16x8*>(&As[wm * 32      + fr][fs * 8]);
                    bf16x8 a1 = *reinterpret_cast<const bf16x8*>(&As[wm * 32 + 16 + fr][fs * 8]);
                    bf16x8 b0 = *reinterpret_cast<const bf16x8*>(&Bs[wn * 32      + fr][fs * 8]);
                    bf16x8 b1 = *reinterpret_cast<const bf16x8*>(&Bs[wn * 32 + 16 + fr][fs * 8]);
                    acc00 = mfma16(a0, b0, acc00);
                    acc01 = mfma16(a0, b1, acc01);
                    acc10 = mfma16(a1, b0, acc10);
                    acc11 = mfma16(a1, b1, acc11);
                }
            }
        }
    }
    const int c0 = co0 + wn * 32 + fr;
    const int c1 = c0 + 16;
    float bi0 = (c0 < Co) ? bias[c0] : 0.f;
    float bi1 = (c1 < Co) ? bias[c1] : 0.f;
    #pragma unroll
    for (int mi = 0; mi < 2; ++mi) {
        f32x4 aN0 = mi ? acc10 : acc00;
        f32x4 aN1 = mi ? acc11 : acc01;
        #pragma unroll
        for (int j = 0; j < 4; ++j) {
            int rm = (mtile << 6) + wm * 32 + mi * 16 + fs * 4 + j;
            size_t vox;
            if (ISCONV) vox = (size_t)rm;
            else {
                int X = rm & ((1 << lw) - 1); int m2 = rm >> lw;
                int Y = m2 & ((1 << lh) - 1); m2 >>= lh;
                int Z = m2 & ((1 << ld) - 1); int nn = m2 >> ld;
                vox = (((size_t)(nn * Do + (2 * Z + pd))) * Ho + (2 * Y + ph)) * Wo + (2 * X + pw);
            }
            if (c0 < Co) out[vox * Co + c0] = f2b(aN0[j] + bi0);
            if (c1 < Co) out[vox * Co + c1] = f2b(aN1[j] + bi1);
        }
    }
}

// ---------------------------------------------------------------------------
// enc1: (2,1,16,256,256) fp32 -> (2,16,128,128,96) bf16 CL, stride (1,2,2).
// ---------------------------------------------------------------------------
__global__ __launch_bounds__(256) void enc1_k(
    const float* __restrict__ x, const float* __restrict__ w,
    const float* __restrict__ bias, u16* __restrict__ out)
{
    __shared__ float Xi[4 * 17 * 33];
    __shared__ float Wl[96 * 27];
    __shared__ float Bl[96];
    const int tid = threadIdx.x;
    int t = blockIdx.x;
    const int tx = t & 7; t >>= 3;
    const int ty = t & 15; t >>= 4;
    const int tz = t;
    const int n = blockIdx.y;
    const int z0 = tz * 2, y0 = ty * 8, x0 = tx * 16;
    for (int i = tid; i < 2592; i += 256) Wl[i] = w[i];
    for (int i = tid; i < 96; i += 256) Bl[i] = bias[i];
    for (int i = tid; i < 2244; i += 256) {
        int fz = i / 561; int r = i - fz * 561; int fy = r / 33; int fx = r - fy * 33;
        int zi = z0 - 1 + fz, yi = 2 * y0 - 1 + fy, xi = 2 * x0 - 1 + fx;
        float v = 0.f;
        if ((unsigned)zi < 16u && (unsigned)yi < 256u && (unsigned)xi < 256u)
            v = x[((size_t)(n * 16 + zi) * 256 + yi) * 256 + xi];
        Xi[i] = v;
    }
    __syncthreads();
    const int lx = tid & 15, ly = (tid >> 4) & 7, lz = tid >> 7;
    float iv[27];
    #pragma unroll
    for (int kd = 0; kd < 3; ++kd)
        #pragma unroll
        for (int kh = 0; kh < 3; ++kh)
            #pragma unroll
            for (int kw = 0; kw < 3; ++kw)
                iv[kd * 9 + kh * 3 + kw] = Xi[(lz + kd) * 561 + (2 * ly + kh) * 33 + (2 * lx + kw)];
    size_t vox = ((size_t)(n * 16 + z0 + lz) * 128 + (y0 + ly)) * 128 + (x0 + lx);
    u16* op = out + vox * 96;
    #pragma unroll
    for (int og = 0; og < 12; ++og) {
        u16x8 pk;
        #pragma unroll
        for (int oo = 0; oo < 8; ++oo) {
            int o = og * 8 + oo;
            float a = Bl[o];
            #pragma unroll
            for (int tp = 0; tp < 27; ++tp) a += iv[tp] * Wl[o * 27 + tp];
            pk[oo] = f2b(a);
        }
        *reinterpret_cast<u16x8*>(op + og * 8) = pk;
    }
}

// ---------------------------------------------------------------------------
// dec4: (2,16,128,128,96) bf16 CL -> (2,1,16,256,256) fp32, per (PH,PW).
// ---------------------------------------------------------------------------
template<int PH, int PW>
__global__ __launch_bounds__(256) void dec4_k(
    const u16* __restrict__ in, const float* __restrict__ w,
    const float* __restrict__ bias, float* __restrict__ out)
{
    constexpr int FH = 8 + PH, FW = 16 + PW, FHW = FH * FW, FTOT = 4 * FHW;
    __shared__ u16 Ai[FTOT][32];
    __shared__ float Wl[96 * 27];
    const int tid = threadIdx.x;
    int t = blockIdx.x;
    const int tx = t & 7; t >>= 3;
    const int ty = t & 15; t >>= 4;
    const int tz = t;
    const int n = blockIdx.y;
    const int z0 = tz * 2, y0 = ty * 8, x0 = tx * 16;
    for (int i = tid; i < 2592; i += 256) Wl[i] = w[i];
    const int lx = tid & 15, ly = (tid >> 4) & 7, lz = tid >> 7;
    float acc = bias[0];
    for (int ci0 = 0; ci0 < 96; ci0 += 32) {
        __syncthreads();
        for (int i = tid; i < FTOT * 4; i += 256) {
            int v = i >> 2, sg = i & 3;
            int fz = v / FHW; int r = v - fz * FHW; int fy = r / FW; int fx = r - fy * FW;
            int zi = z0 - 1 + fz, yi = y0 + fy, xi = x0 + fx;
            uint4 vv = {0,0,0,0};
            if ((unsigned)zi < 16u && (unsigned)yi < 128u && (unsigned)xi < 128u)
                vv = *reinterpret_cast<const uint4*>(
                    in + (((size_t)(n * 16 + zi) * 128 + yi) * 128 + xi) * 96 + ci0 + sg * 8);
            *reinterpret_cast<uint4*>(&Ai[v][sg * 8]) = vv;
        }
        __syncthreads();
        #pragma unroll
        for (int jd = 0; jd < 3; ++jd) {
            #pragma unroll
            for (int jh = 0; jh <= PH; ++jh) {
                #pragma unroll
                for (int jw = 0; jw <= PW; ++jw) {
                    int v = (lz + jd) * FHW + (ly + jh) * FW + (lx + jw);
                    int wd = 2 - jd;
                    int wh = PH ? (jh ? 0 : 2) : 1;
                    int ww = PW ? (jw ? 0 : 2) : 1;
                    int wtap = wd * 9 + wh * 3 + ww;
                    const u16* ap = &Ai[v][0];
                    #pragma unroll
                    for (int c8 = 0; c8 < 4; ++c8) {
                        bf16x8 iv8 = *reinterpret_cast<const bf16x8*>(ap + c8 * 8);
                        #pragma unroll
                        for (int e = 0; e < 8; ++e)
                            acc += (float)iv8[e] * Wl[(ci0 + c8 * 8 + e) * 27 + wtap];
                    }
                }
            }
        }
    }
    const int Z = z0 + lz, Y = 2 * (y0 + ly) + PH, X = 2 * (x0 + lx) + PW;
    out[((size_t)(n * 16 + Z) * 256 + Y) * 256 + X] = acc;
}

// ---------------------------------------------------------------------------
// BN stats, deterministic two-stage LDS reduction (no atomics).
// ---------------------------------------------------------------------------
__global__ __launch_bounds__(256) void bnstat_k(
    const u16* __restrict__ a, float* __restrict__ pm, float* __restrict__ pv,
    int C, unsigned total8)
{
    __shared__ float sS[256][8];
    __shared__ float sQ[256][8];
    unsigned g = blockIdx.x * 256 + threadIdx.x;
    unsigned stride = gridDim.x * 256;
    float s[8] = {0,0,0,0,0,0,0,0}, q[8] = {0,0,0,0,0,0,0,0};
    for (unsigned i = g; i < total8; i += stride) {
        uint4 v = *reinterpret_cast<const uint4*>(a + (size_t)i * 8);
        float f[8]; unp8(v, f);
        #pragma unroll
        for (int e = 0; e < 8; ++e) { s[e] += f[e]; q[e] += f[e] * f[e]; }
    }
    #pragma unroll
    for (int e = 0; e < 8; ++e) { sS[threadIdx.x][e] = s[e]; sQ[threadIdx.x][e] = q[e]; }
    __syncthreads();
    int c = threadIdx.x;
    if (c < C) {
        int C8 = C >> 3;
        int B = (int)((blockIdx.x * 2048u) % (unsigned)C);
        int r = c - B; r %= C; if (r < 0) r += C;
        int e = r & 7, t0 = r >> 3;
        float S = 0.f, Q = 0.f;
        for (int tt = t0; tt < 256; tt += C8) { S += sS[tt][e]; Q += sQ[tt][e]; }
        pm[blockIdx.x * C + c] = S;
        pv[blockIdx.x * C + c] = Q;
    }
}

// parallel finalize: grid = C blocks, 64 threads reduce G partials
__global__ __launch_bounds__(64) void bnfin_k(
    const float* __restrict__ pm, const float* __restrict__ pv,
    const float* __restrict__ g, const float* __restrict__ be,
    float* __restrict__ sc, float* __restrict__ sb, int C, int G, float invcnt)
{
    int c = blockIdx.x;
    float S = 0.f, Q = 0.f;
    for (int b = threadIdx.x; b < G; b += 64) { S += pm[b * C + c]; Q += pv[b * C + c]; }
    #pragma unroll
    for (int off = 32; off; off >>= 1) {
        S += __shfl_down(S, off, 64);
        Q += __shfl_down(Q, off, 64);
    }
    if (threadIdx.x == 0) {
        float m = S * invcnt;
        float v = Q * invcnt - m * m;
        float s = g[c] * rsqrtf(v + 1e-5f);
        sc[c] = s; sb[c] = be[c] - m * s;
    }
}

__global__ __launch_bounds__(256) void bnapply_k(
    u16* __restrict__ a, const float* __restrict__ sc, const float* __restrict__ sb,
    int C, unsigned total8)
{
    unsigned g = blockIdx.x * 256 + threadIdx.x;
    unsigned stride = gridDim.x * 256;
    int c0 = (int)((g * 8u) % (unsigned)C);
    float lsc[8], lsb[8];
    #pragma unroll
    for (int e = 0; e < 8; ++e) { lsc[e] = sc[c0 + e]; lsb[e] = sb[c0 + e]; }
    for (unsigned i = g; i < total8; i += stride) {
        uint4 v = *reinterpret_cast<const uint4*>(a + (size_t)i * 8);
        float f[8]; unp8(v, f);
        u16x8 pk;
        #pragma unroll
        for (int e = 0; e < 8; ++e) {
            float y = f[e] * lsc[e] + lsb[e];
            y = y >= 0.f ? y : 0.2f * y;
            pk[e] = f2b(y);
        }
        *reinterpret_cast<u16x8*>(a + (size_t)i * 8) = pk;
    }
}

// ---------------------------------------------------------------------------
// memprep: mem fp32 [2000][256] -> memb bf16, memT bf16 [256][2048] (padded),
// mnorm [2000]. grid 2048 x 256 thr.
// ---------------------------------------------------------------------------
__global__ __launch_bounds__(256) void memprep_k(
    const float* __restrict__ mem, u16* __restrict__ memb, u16* __restrict__ memT,
    float* __restrict__ mnorm)
{
    int k = blockIdx.x, c = threadIdx.x;
    if (k >= 2000) { memT[(size_t)c * 2048 + k] = 0; return; }
    float v = mem[(size_t)k * 256 + c];
    u16 b = f2b(v);
    memb[(size_t)k * 256 + c] = b;
    memT[(size_t)c * 2048 + k] = b;
    float s = v * v;
    #pragma unroll
    for (int off = 32; off; off >>= 1) s += __shfl_down(s, off, 64);
    __shared__ float red[4];
    if ((c & 63) == 0) red[c >> 6] = s;
    __syncthreads();
    if (c == 0) mnorm[k] = sqrtf(red[0] + red[1] + red[2] + red[3]);
}

// z row norms: b4 [1024][256] bf16 -> znorm [1024]. grid 1024 x 64 thr.
__global__ __launch_bounds__(64) void znorm_k(
    const u16* __restrict__ z, float* __restrict__ znorm)
{
    int m = blockIdx.x, l = threadIdx.x;
    ushort4 v = *reinterpret_cast<const ushort4*>(z + (size_t)m * 256 + l * 4);
    float a = b2f(v.x), b = b2f(v.y), cc = b2f(v.z), d = b2f(v.w);
    float s = a * a + b * b + cc * cc + d * d;
    #pragma unroll
    for (int off = 32; off; off >>= 1) s += __shfl_down(s, off, 64);
    if (l == 0) znorm[m] = sqrtf(s);
}

// scores GEMM: M=1024, N=2000, K=256. grid (16, 32).
__global__ __launch_bounds__(256) void scores_mfma_k(
    const u16* __restrict__ z, const u16* __restrict__ memb,
    const float* __restrict__ znorm, const float* __restrict__ mnorm,
    float* __restrict__ scores)
{
    __shared__ u16 As[64][40];
    __shared__ u16 Bs[64][40];
    const int tid = threadIdx.x;
    const int m0 = blockIdx.x << 6, n0 = blockIdx.y << 6;
    const int arow = tid >> 2, seg = tid & 3;
    const bool bok = (n0 + arow) < 2000;
    const int wave = tid >> 6, lane = tid & 63;
    const int wm = wave >> 1, wn = wave & 1, fr = lane & 15, fs = lane >> 4;
    f32x4 acc00 = {0,0,0,0}, acc01 = {0,0,0,0}, acc10 = {0,0,0,0}, acc11 = {0,0,0,0};
    for (int k0 = 0; k0 < 256; k0 += 32) {
        uint4 avv = *reinterpret_cast<const uint4*>(z + (size_t)(m0 + arow) * 256 + k0 + seg * 8);
        uint4 bvv = {0,0,0,0};
        if (bok) bvv = *reinterpret_cast<const uint4*>(memb + (size_t)(n0 + arow) * 256 + k0 + seg * 8);
        __syncthreads();
        *reinterpret_cast<uint4*>(&As[arow][seg * 8]) = avv;
        *reinterpret_cast<uint4*>(&Bs[arow][seg * 8]) = bvv;
        __syncthreads();
        bf16x8 a0 = *reinterpret_cast<const bf16x8*>(&As[wm * 32      + fr][fs * 8]);
        bf16x8 a1 = *reinterpret_cast<const bf16x8*>(&As[wm * 32 + 16 + fr][fs * 8]);
        bf16x8 b0 = *reinterpret_cast<const bf16x8*>(&Bs[wn * 32      + fr][fs * 8]);
        bf16x8 b1 = *reinterpret_cast<const bf16x8*>(&Bs[wn * 32 + 16 + fr][fs * 8]);
        acc00 = mfma16(a0, b0, acc00);
        acc01 = mfma16(a0, b1, acc01);
        acc10 = mfma16(a1, b0, acc10);
        acc11 = mfma16(a1, b1, acc11);
    }
    const int c0 = n0 + wn * 32 + fr, c1 = c0 + 16;
    float mn0 = (c0 < 2000) ? mnorm[c0] : 1.f;
    float mn1 = (c1 < 2000) ? mnorm[c1] : 1.f;
    #pragma unroll
    for (int mi = 0; mi < 2; ++mi) {
        f32x4 aN0 = mi ? acc10 : acc00;
        f32x4 aN1 = mi ? acc11 : acc01;
        #pragma unroll
        for (int j = 0; j < 4; ++j) {
            int rm = m0 + wm * 32 + mi * 16 + fs * 4 + j;
            float zn = znorm[rm];
            if (c0 < 2000) scores[(size_t)rm * 2000 + c0] = aN0[j] / fmaxf(zn * mn0, 1e-8f);
            if (c1 < 2000) scores[(size_t)rm * 2000 + c1] = aN1[j] / fmaxf(zn * mn1, 1e-8f);
        }
    }
}

// single-pass register softmax over K=2000 (=250x8). Writes fp32 w (output)
// and bf16 copy wb16 [1024][2048] zero-padded. grid 1024 x 256 thr.
__global__ __launch_bounds__(256) void softmax2_k(
    float* __restrict__ w, u16* __restrict__ wb16)
{
    __shared__ float red[4];
    const int m = blockIdx.x, t = threadIdx.x;
    const bool act = t < 250;
    float v[8];
    if (act) {
        float4 p0 = *reinterpret_cast<const float4*>(w + (size_t)m * 2000 + t * 8);
        float4 p1 = *reinterpret_cast<const float4*>(w + (size_t)m * 2000 + t * 8 + 4);
        v[0]=p0.x; v[1]=p0.y; v[2]=p0.z; v[3]=p0.w;
        v[4]=p1.x; v[5]=p1.y; v[6]=p1.z; v[7]=p1.w;
    } else {
        for (int i = 0; i < 8; ++i) v[i] = -1e30f;
    }
    float mx = -1e30f;
    for (int i = 0; i < 8; ++i) mx = fmaxf(mx, v[i]);
    #pragma unroll
    for (int off = 32; off; off >>= 1) mx = fmaxf(mx, __shfl_down(mx, off, 64));
    if ((t & 63) == 0) red[t >> 6] = mx;
    __syncthreads();
    mx = fmaxf(fmaxf(red[0], red[1]), fmaxf(red[2], red[3]));
    __syncthreads();
    float e[8], sm = 0.f;
    for (int i = 0; i < 8; ++i) {
        e[i] = act ? expf(v[i] - mx) : 0.f;
        sm += e[i];
    }
    #pragma unroll
    for (int off = 32; off; off >>= 1) sm += __shfl_down(sm, off, 64);
    if ((t & 63) == 0) red[t >> 6] = sm;
    __syncthreads();
    float inv = 1.0f / (red[0] + red[1] + red[2] + red[3]);
    u16x8 pk = {0,0,0,0,0,0,0,0};
    if (act) {
        float r[8];
        for (int i = 0; i < 8; ++i) { r[i] = e[i] * inv; pk[i] = f2b(r[i]); }
        float4 o0, o1;
        o0.x=r[0]; o0.y=r[1]; o0.z=r[2]; o0.w=r[3];
        o1.x=r[4]; o1.y=r[5]; o1.z=r[6]; o1.w=r[7];
        *reinterpret_cast<float4*>(w + (size_t)m * 2000 + t * 8)     = o0;
        *reinterpret_cast<float4*>(w + (size_t)m * 2000 + t * 8 + 4) = o1;
    }
    *reinterpret_cast<u16x8*>(wb16 + (size_t)m * 2048 + t * 8) = pk;
}

// zhat GEMM: M=1024, N=256, K=2048 (padded). A=wb16, B=memT. out zf bf16 CL.
__global__ __launch_bounds__(256) void zhat_mfma_k(
    const u16* __restrict__ wb16, const u16* __restrict__ memT,
    u16* __restrict__ zf)
{
    __shared__ u16 As[64][40];
    __shared__ u16 Bs[64][40];
    const int tid = threadIdx.x;
    const int m0 = blockIdx.x << 6, n0 = blockIdx.y << 6;
    const int arow = tid >> 2, seg = tid & 3;
    const int wave = tid >> 6, lane = tid & 63;
    const int wm = wave >> 1, wn = wave & 1, fr = lane & 15, fs = lane >> 4;
    f32x4 acc00 = {0,0,0,0}, acc01 = {0,0,0,0}, acc10 = {0,0,0,0}, acc11 = {0,0,0,0};
    for (int k0 = 0; k0 < 2048; k0 += 32) {
        uint4 avv = *reinterpret_cast<const uint4*>(wb16 + (size_t)(m0 + arow) * 2048 + k0 + seg * 8);
        uint4 bvv = *reinterpret_cast<const uint4*>(memT + (size_t)(n0 + arow) * 2048 + k0 + seg * 8);
        __syncthreads();
        *reinterpret_cast<uint4*>(&As[arow][seg * 8]) = avv;
        *reinterpret_cast<uint4*>(&Bs[arow][seg * 8]) = bvv;
        __syncthreads();
        bf16x8 a0 = *reinterpret_cast<const bf16x8*>(&As[wm * 32      + fr][fs * 8]);
        bf16x8 a1 = *reinterpret_cast<const bf16x8*>(&As[wm * 32 + 16 + fr][fs * 8]);
        bf16x8 b0 = *reinterpret_cast<const bf16x8*>(&Bs[wn * 32      + fr][fs * 8]);
        bf16x8 b1 = *reinterpret_cast<const bf16x8*>(&Bs[wn * 32 + 16 + fr][fs * 8]);
        acc00 = mfma16(a0, b0, acc00);
        acc01 = mfma16(a0, b1, acc01);
        acc10 = mfma16(a1, b0, acc10);
        acc11 = mfma16(a1, b1, acc11);
    }
    const int c0 = n0 + wn * 32 + fr, c1 = c0 + 16;
    #pragma unroll
    for (int mi = 0; mi < 2; ++mi) {
        f32x4 aN0 = mi ? acc10 : acc00;
        f32x4 aN1 = mi ? acc11 : acc01;
        #pragma unroll
        for (int j = 0; j < 4; ++j) {
            int rm = m0 + wm * 32 + mi * 16 + fs * 4 + j;
            zf[(size_t)rm * 256 + c0] = f2b(aN0[j]);
            zf[(size_t)rm * 256 + c1] = f2b(aN1[j]);
        }
    }
}

// ---------------------------------------------------------------------------
// launch
// ---------------------------------------------------------------------------
extern "C" void kernel_launch(void* const* d_in, const int* in_sizes, int n_in,
                              void* d_out, int out_size, void* d_ws, size_t ws_size,
                              hipStream_t stream)
{
    const float* x     = (const float*)d_in[0];
    const float* ew[4] = { (const float*)d_in[1],  (const float*)d_in[5],
                           (const float*)d_in[9],  (const float*)d_in[13] };
    const float* eb[4] = { (const float*)d_in[2],  (const float*)d_in[6],
                           (const float*)d_in[10], (const float*)d_in[14] };
    const float* eg[4] = { (const float*)d_in[3],  (const float*)d_in[7],
                           (const float*)d_in[11], (const float*)d_in[15] };
    const float* ebe[4]= { (const float*)d_in[4],  (const float*)d_in[8],
                           (const float*)d_in[12], (const float*)d_in[16] };
    const float* mem   = (const float*)d_in[17];
    const float* dw[4] = { (const float*)d_in[18], (const float*)d_in[22],
                           (const float*)d_in[26], (const float*)d_in[30] };
    const float* db[4] = { (const float*)d_in[19], (const float*)d_in[23],
                           (const float*)d_in[27], (const float*)d_in[31] };
    const float* dg[3] = { (const float*)d_in[20], (const float*)d_in[24],
                           (const float*)d_in[28] };
    const float* dbe[3]= { (const float*)d_in[21], (const float*)d_in[25],
                           (const float*)d_in[29] };

    float* outp  = (float*)d_out;
    float* w_out = (float*)d_out + 2097152;

    char* p = (char*)d_ws;
    auto take = [&](size_t bytes) -> char* {
        char* q = p; p += (bytes + 255) & ~(size_t)255; return q;
    };
    u16* b1   = (u16*)take(50331648ull * 2);
    u16* b2   = (u16*)take(8388608ull * 2);
    u16* b3   = (u16*)take(2097152ull * 2);
    u16* b4   = (u16*)take(262144ull * 2);
    u16* zf   = (u16*)take(262144ull * 2);
    u16* w2   = (u16*)take(331776ull * 2);
    u16* w3   = (u16*)take(884736ull * 2);
    u16* w4   = (u16*)take(1769472ull * 2);
    u16* wd1  = (u16*)take(1769472ull * 2);
    u16* wd2  = (u16*)take(884736ull * 2);
    u16* wd3  = (u16*)take(331776ull * 2);
    u16* memb = (u16*)take(512000ull * 2);
    u16* memT = (u16*)take(524288ull * 2);
    u16* wb16 = (u16*)take(2097152ull * 2);
    float* pm    = (float*)take(131072 * 4);
    float* pv    = (float*)take(131072 * 4);
    float* scb   = (float*)take(512 * 4);
    float* mnorm = (float*)take(2048 * 4);
    float* znorm = (float*)take(1024 * 4);

    auto bn = [&](u16* buf, const float* g, const float* be, int C, unsigned total8, int G) {
        bnstat_k<<<G, 256, 0, stream>>>(buf, pm, pv, C, total8);
        bnfin_k<<<C, 64, 0, stream>>>(pm, pv, g, be, scb, scb + 256, C, G,
                                      (float)C / ((float)total8 * 8.0f));
        bnapply_k<<<G, 256, 0, stream>>>(buf, scb, scb + 256, C, total8);
    };

    // ---- weight + memory prep ----
    repack_k<<<256, 256, 0, stream>>>(ew[1], w2, 128, 96);
    repack_k<<<256, 256, 0, stream>>>(ew[2], w3, 256, 128);
    repack_k<<<256, 256, 0, stream>>>(ew[3], w4, 256, 256);
    repack_k<<<256, 256, 0, stream>>>(dw[0], wd1, 256, 256);
    repack_k<<<256, 256, 0, stream>>>(dw[1], wd2, 128, 256);
    repack_k<<<256, 256, 0, stream>>>(dw[2], wd3, 96, 128);
    memprep_k<<<2048, 256, 0, stream>>>(mem, memb, memT, mnorm);

    // ---- encoder ----
    enc1_k<<<dim3(1024, 2), 256, 0, stream>>>(x, ew[0], eb[0], b1);
    bn(b1, eg[0], ebe[0], 96, 6291456u, 768);

    conv_mfma_k<true><<<dim3(1024, 2, 1), 256, 0, stream>>>(
        b1, w2, eb[1], b2, 96, 128, 16, 128, 128, 3, 6, 6, 8, 64, 64);
    bn(b2, eg[1], ebe[1], 128, 1048576u, 512);

    conv_mfma_k<true><<<dim3(128, 4, 1), 256, 0, stream>>>(
        b2, w3, eb[2], b3, 128, 256, 8, 64, 64, 2, 5, 5, 4, 32, 32);
    bn(b3, eg[2], ebe[2], 256, 262144u, 512);

    conv_mfma_k<true><<<dim3(16, 4, 1), 256, 0, stream>>>(
        b3, w4, eb[3], b4, 256, 256, 4, 32, 32, 1, 4, 4, 2, 16, 16);
    bn(b4, eg[3], ebe[3], 256, 32768u, 128);

    // ---- memory module (MFMA) ----
    znorm_k<<<1024, 64, 0, stream>>>(b4, znorm);
    scores_mfma_k<<<dim3(16, 32), 256, 0, stream>>>(b4, memb, znorm, mnorm, w_out);
    softmax2_k<<<1024, 256, 0, stream>>>(w_out, wb16);
    zhat_mfma_k<<<dim3(16, 4), 256, 0, stream>>>(wb16, memT, zf);

    // ---- decoder ----
    conv_mfma_k<false><<<dim3(16, 4, 8), 256, 0, stream>>>(
        zf, wd1, db[0], b3, 256, 256, 2, 16, 16, 1, 4, 4, 4, 32, 32);
    bn(b3, dg[0], dbe[0], 256, 262144u, 512);

    conv_mfma_k<false><<<dim3(128, 2, 8), 256, 0, stream>>>(
        b3, wd2, db[1], b2, 256, 128, 4, 32, 32, 2, 5, 5, 8, 64, 64);
    bn(b2, dg[1], dbe[1], 128, 1048576u, 512);

    conv_mfma_k<false><<<dim3(1024, 2, 8), 256, 0, stream>>>(
        b2, wd3, db[2], b1, 128, 96, 8, 64, 64, 3, 6, 6, 16, 128, 128);
    bn(b1, dg[2], dbe[2], 96, 6291456u, 768);

    dec4_k<0,0><<<dim3(1024, 2), 256, 0, stream>>>(b1, dw[3], db[3], outp);
    dec4_k<0,1><<<dim3(1024, 2), 256, 0, stream>>>(b1, dw[3], db[3], outp);
    dec4_k<1,0><<<dim3(1024, 2), 256, 0, stream>>>(b1, dw[3], db[3], outp);
    dec4_k<1,1><<<dim3(1024, 2), 256, 0, stream>>>(b1, dw[3], db[3], outp);
}